// Round 1
// baseline (783.736 us; speedup 1.0000x reference)
//
#include <hip/hip_runtime.h>
#include <math.h>

#define BN_EPS 1e-5f
constexpr int CAP = 64;  // max neighbors/node incl self-loop; deg~Poisson(16), P(>63)~0

// ---------------- CSR build (padded, by dst) ----------------
__global__ __launch_bounds__(256) void k_selfloop(int* __restrict__ col, int* __restrict__ cnt, int N) {
    int i = blockIdx.x * 256 + threadIdx.x;
    if (i < N) { col[(size_t)i * CAP] = i; cnt[i] = 1; }
}

__global__ __launch_bounds__(256) void k_fill(const int* __restrict__ ei, int* __restrict__ col,
                                              int* __restrict__ cnt, int E) {
    int e = blockIdx.x * 256 + threadIdx.x;
    if (e < E) {
        int s = ei[e];
        int d = ei[E + e];
        int pos = atomicAdd(&cnt[d], 1);
        if (pos < CAP) col[(size_t)d * CAP + pos] = s;
    }
}

__global__ __launch_bounds__(256) void k_dinv(const int* __restrict__ cnt, float* __restrict__ dinv, int N) {
    int i = blockIdx.x * 256 + threadIdx.x;
    if (i < N) dinv[i] = rsqrtf((float)cnt[i]);
}

// ---------------- fused GEMM: out = rowscale * relu?( (in@w + bias) folded BN ) ----------------
// block = 256 threads, 128 rows/block (2 rows/thread), 4 col-groups/row.
// Column mapping col = c4*16 + cg*4 + j  -> conflict-free LDS b128 reads (4 cgs cover 16 consec floats).
template <int FIN, int FOUT, bool RELU, bool BN>
__global__ __launch_bounds__(256) void gemm_kernel(
    const float* __restrict__ in, const float* __restrict__ w,
    const float* __restrict__ bias,
    const float* __restrict__ g, const float* __restrict__ beta,
    const float* __restrict__ mm, const float* __restrict__ vv,
    const float* __restrict__ rowscale,
    float* __restrict__ out, int N)
{
    constexpr int KT = 32;
    constexpr int COLS = FOUT / 4;
    __shared__ float lw[KT * FOUT];
    __shared__ float cs[FOUT];
    __shared__ float ct[FOUT];

    const int tid = threadIdx.x;
    const int cg = tid & 3;
    const int rr = tid >> 2;
    const int r0 = blockIdx.x * 128 + rr;
    const int r1 = r0 + 64;
    const int r0c = min(r0, N - 1);
    const int r1c = min(r1, N - 1);

    if (tid < FOUT) {
        float s = 1.f, t = 0.f;
        if constexpr (BN) {
            s = g[tid] * rsqrtf(vv[tid] + BN_EPS);
            t = beta[tid] - mm[tid] * s;
        }
        float bb = bias ? bias[tid] : 0.f;
        cs[tid] = s;
        ct[tid] = bb * s + t;
    }

    float acc0[COLS], acc1[COLS];
#pragma unroll
    for (int c = 0; c < COLS; ++c) { acc0[c] = 0.f; acc1[c] = 0.f; }

    const float4* in4_0 = (const float4*)(in + (size_t)r0c * FIN);
    const float4* in4_1 = (const float4*)(in + (size_t)r1c * FIN);

    for (int k0 = 0; k0 < FIN; k0 += KT) {
        __syncthreads();
        const float4* wsrc = (const float4*)(w + (size_t)k0 * FOUT);
        float4* ldst = (float4*)lw;
#pragma unroll
        for (int i = 0; i < KT * FOUT / 4 / 256; ++i)
            ldst[tid + i * 256] = wsrc[tid + i * 256];
        __syncthreads();

#pragma unroll
        for (int kk = 0; kk < KT; kk += 4) {
            float4 a = in4_0[(k0 + kk) >> 2];
            float4 b = in4_1[(k0 + kk) >> 2];
            float av[4] = {a.x, a.y, a.z, a.w};
            float bv[4] = {b.x, b.y, b.z, b.w};
#pragma unroll
            for (int j = 0; j < 4; ++j) {
                const float4* wrow = (const float4*)&lw[(kk + j) * FOUT];
#pragma unroll
                for (int c4 = 0; c4 < COLS / 4; ++c4) {
                    float4 wvv = wrow[c4 * 4 + cg];
                    acc0[c4 * 4 + 0] += av[j] * wvv.x; acc1[c4 * 4 + 0] += bv[j] * wvv.x;
                    acc0[c4 * 4 + 1] += av[j] * wvv.y; acc1[c4 * 4 + 1] += bv[j] * wvv.y;
                    acc0[c4 * 4 + 2] += av[j] * wvv.z; acc1[c4 * 4 + 2] += bv[j] * wvv.z;
                    acc0[c4 * 4 + 3] += av[j] * wvv.w; acc1[c4 * 4 + 3] += bv[j] * wvv.w;
                }
            }
        }
    }

    if (r0 < N) {
        float sc = rowscale ? rowscale[r0] : 1.f;
        float4* o = (float4*)(out + (size_t)r0 * FOUT);
#pragma unroll
        for (int c4 = 0; c4 < COLS / 4; ++c4) {
            int colb = c4 * 16 + cg * 4;
            float z0 = acc0[c4 * 4 + 0] * cs[colb + 0] + ct[colb + 0];
            float z1 = acc0[c4 * 4 + 1] * cs[colb + 1] + ct[colb + 1];
            float z2 = acc0[c4 * 4 + 2] * cs[colb + 2] + ct[colb + 2];
            float z3 = acc0[c4 * 4 + 3] * cs[colb + 3] + ct[colb + 3];
            if constexpr (RELU) { z0 = fmaxf(z0, 0.f); z1 = fmaxf(z1, 0.f); z2 = fmaxf(z2, 0.f); z3 = fmaxf(z3, 0.f); }
            float4 zz = {z0 * sc, z1 * sc, z2 * sc, z3 * sc};
            o[c4 * 4 + cg] = zz;
        }
    }
    if (r1 < N) {
        float sc = rowscale ? rowscale[r1] : 1.f;
        float4* o = (float4*)(out + (size_t)r1 * FOUT);
#pragma unroll
        for (int c4 = 0; c4 < COLS / 4; ++c4) {
            int colb = c4 * 16 + cg * 4;
            float z0 = acc1[c4 * 4 + 0] * cs[colb + 0] + ct[colb + 0];
            float z1 = acc1[c4 * 4 + 1] * cs[colb + 1] + ct[colb + 1];
            float z2 = acc1[c4 * 4 + 2] * cs[colb + 2] + ct[colb + 2];
            float z3 = acc1[c4 * 4 + 3] * cs[colb + 3] + ct[colb + 3];
            if constexpr (RELU) { z0 = fmaxf(z0, 0.f); z1 = fmaxf(z1, 0.f); z2 = fmaxf(z2, 0.f); z3 = fmaxf(z3, 0.f); }
            float4 zz = {z0 * sc, z1 * sc, z2 * sc, z3 * sc};
            o[c4 * 4 + cg] = zz;
        }
    }
}

// ---------------- aggregation: hout[i] = dinv[i] * sum_{j in row(i)} hin[j]  ----------------
// (dinv[j] pre-folded into hin rows by producer epilogue). One wave per node.
template <int F>
__global__ __launch_bounds__(256) void agg_kernel(
    const float* __restrict__ hin, float* __restrict__ hout,
    const int* __restrict__ col, const int* __restrict__ cnt,
    const float* __restrict__ dinv, int N)
{
    const int wave = (blockIdx.x * 256 + threadIdx.x) >> 6;
    const int lane = threadIdx.x & 63;
    if (wave >= N) return;
    const int n = min(cnt[wave], CAP);
    const int* __restrict__ c = col + (size_t)wave * CAP;

    if constexpr (F == 128) {
        float2 acc = {0.f, 0.f};
        int p = 0;
        for (; p + 2 <= n; p += 2) {
            int j0 = c[p], j1 = c[p + 1];
            const float2* r0 = (const float2*)(hin + (size_t)j0 * 128);
            const float2* r1 = (const float2*)(hin + (size_t)j1 * 128);
            float2 x0 = r0[lane];
            float2 x1 = r1[lane];
            acc.x += x0.x + x1.x;
            acc.y += x0.y + x1.y;
        }
        if (p < n) {
            const float2* r0 = (const float2*)(hin + (size_t)c[p] * 128);
            float2 x0 = r0[lane];
            acc.x += x0.x;
            acc.y += x0.y;
        }
        float d = dinv[wave];
        float2 res = {acc.x * d, acc.y * d};
        ((float2*)(hout + (size_t)wave * 128))[lane] = res;
    } else {
        float acc = 0.f;
        int p = 0;
        for (; p + 2 <= n; p += 2) {
            int j0 = c[p], j1 = c[p + 1];
            float x0 = hin[(size_t)j0 * F + lane];
            float x1 = hin[(size_t)j1 * F + lane];
            acc += x0 + x1;
        }
        if (p < n) acc += hin[(size_t)c[p] * F + lane];
        hout[(size_t)wave * F + lane] = acc * dinv[wave];
    }
}

// ---------------- final: bias3 + BN3 + ReLU + (64x8 GEMM) + log_softmax ----------------
__global__ __launch_bounds__(256) void final_kernel(
    const float* __restrict__ a3,
    const float* __restrict__ b3, const float* __restrict__ g3, const float* __restrict__ beta3,
    const float* __restrict__ m3, const float* __restrict__ v3,
    const float* __restrict__ w_out, const float* __restrict__ b_out,
    float* __restrict__ out, int N)
{
    __shared__ float sw[64 * 8];
    __shared__ float S[64];
    __shared__ float T[64];
    __shared__ float sb[8];
    const int tid = threadIdx.x;
    if (tid < 64) {
        float s = g3[tid] * rsqrtf(v3[tid] + BN_EPS);
        S[tid] = s;
        T[tid] = b3[tid] * s + beta3[tid] - m3[tid] * s;
    }
    if (tid < 8) sb[tid] = b_out[tid];
    sw[tid] = w_out[tid];
    sw[tid + 256] = w_out[tid + 256];
    __syncthreads();

    const int i = blockIdx.x * 256 + tid;
    if (i >= N) return;

    const float4* row = (const float4*)(a3 + (size_t)i * 64);
    float lg[8];
#pragma unroll
    for (int cc = 0; cc < 8; ++cc) lg[cc] = sb[cc];
#pragma unroll
    for (int f4 = 0; f4 < 16; ++f4) {
        float4 av = row[f4];
        float a[4] = {av.x, av.y, av.z, av.w};
#pragma unroll
        for (int j = 0; j < 4; ++j) {
            int f = f4 * 4 + j;
            float z = a[j] * S[f] + T[f];
            z = fmaxf(z, 0.f);
#pragma unroll
            for (int cc = 0; cc < 8; ++cc) lg[cc] += z * sw[f * 8 + cc];
        }
    }
    float mx = lg[0];
#pragma unroll
    for (int cc = 1; cc < 8; ++cc) mx = fmaxf(mx, lg[cc]);
    float sum = 0.f;
#pragma unroll
    for (int cc = 0; cc < 8; ++cc) sum += expf(lg[cc] - mx);
    float lse = logf(sum) + mx;
    float4 o0 = {lg[0] - lse, lg[1] - lse, lg[2] - lse, lg[3] - lse};
    float4 o1 = {lg[4] - lse, lg[5] - lse, lg[6] - lse, lg[7] - lse};
    float4* op = (float4*)(out + (size_t)i * 8);
    op[0] = o0;
    op[1] = o1;
}

extern "C" void kernel_launch(void* const* d_in, const int* in_sizes, int n_in,
                              void* d_out, int out_size, void* d_ws, size_t ws_size,
                              hipStream_t stream) {
    const float* x     = (const float*)d_in[0];
    const int*   ei    = (const int*)d_in[1];
    const float* w_in  = (const float*)d_in[2];
    const float* b_in  = (const float*)d_in[3];
    const float* w1    = (const float*)d_in[4];
    const float* b1    = (const float*)d_in[5];
    const float* w2    = (const float*)d_in[6];
    const float* b2    = (const float*)d_in[7];
    const float* w3    = (const float*)d_in[8];
    const float* b3    = (const float*)d_in[9];
    const float* w_o   = (const float*)d_in[10];
    const float* b_o   = (const float*)d_in[11];
    const float* g1    = (const float*)d_in[12];
    const float* be1   = (const float*)d_in[13];
    const float* m1    = (const float*)d_in[14];
    const float* v1    = (const float*)d_in[15];
    const float* g2    = (const float*)d_in[16];
    const float* be2   = (const float*)d_in[17];
    const float* m2    = (const float*)d_in[18];
    const float* v2    = (const float*)d_in[19];
    const float* g3    = (const float*)d_in[20];
    const float* be3   = (const float*)d_in[21];
    const float* m3    = (const float*)d_in[22];
    const float* v3    = (const float*)d_in[23];

    const int N = in_sizes[0] / 128;
    const int E = in_sizes[1] / 2;

    char* p = (char*)d_ws;
    auto alloc = [&](size_t bytes) {
        void* r = (void*)p;
        p += (bytes + 255) & ~(size_t)255;
        return r;
    };
    int*   cnt  = (int*)alloc((size_t)N * 4);
    float* dinv = (float*)alloc((size_t)N * 4);
    int*   col  = (int*)alloc((size_t)N * CAP * 4);
    float* bufA = (float*)alloc((size_t)N * 128 * 4);
    float* bufB = (float*)alloc((size_t)N * 128 * 4);

    const int gN = (N + 255) / 256;
    const int gE = (E + 255) / 256;
    const int gG = (N + 127) / 128;   // gemm: 128 rows/block
    const int gA = (N + 3) / 4;       // agg: 4 nodes/block (wave per node)

    // CSR build
    k_selfloop<<<gN, 256, 0, stream>>>(col, cnt, N);
    k_fill<<<gE, 256, 0, stream>>>(ei, col, cnt, E);
    k_dinv<<<gN, 256, 0, stream>>>(cnt, dinv, N);

    // h0s = dinv * relu(x @ w_in + b_in)                       [N,64]  -> bufA
    gemm_kernel<128, 64, true, false><<<gG, 256, 0, stream>>>(
        x, w_in, b_in, nullptr, nullptr, nullptr, nullptr, dinv, bufA, N);
    // a1 = A_hat @ h0                                          [N,64]  -> bufB
    agg_kernel<64><<<gA, 256, 0, stream>>>(bufA, bufB, col, cnt, dinv, N);
    // h1s = dinv * relu(bn1(a1 @ w1 + b1))                     [N,128] -> bufA
    gemm_kernel<64, 128, true, true><<<gG, 256, 0, stream>>>(
        bufB, w1, b1, g1, be1, m1, v1, dinv, bufA, N);
    // a2 = A_hat @ h1                                          [N,128] -> bufB
    agg_kernel<128><<<gA, 256, 0, stream>>>(bufA, bufB, col, cnt, dinv, N);
    // h2 = relu(bn2(a2 @ w2 + b2))   (unscaled)                [N,128] -> bufA
    gemm_kernel<128, 128, true, true><<<gG, 256, 0, stream>>>(
        bufB, w2, b2, g2, be2, m2, v2, nullptr, bufA, N);
    // t3s = dinv * (h2 @ w3)                                   [N,64]  -> bufB
    gemm_kernel<128, 64, false, false><<<gG, 256, 0, stream>>>(
        bufA, w3, nullptr, nullptr, nullptr, nullptr, nullptr, dinv, bufB, N);
    // a3 = A_hat @ t3                                          [N,64]  -> bufA
    agg_kernel<64><<<gA, 256, 0, stream>>>(bufB, bufA, col, cnt, dinv, N);
    // out = log_softmax(relu(bn3(a3 + b3)) @ w_out + b_out)    [N,8]
    final_kernel<<<gN, 256, 0, stream>>>(bufA, b3, g3, be3, m3, v3, w_o, b_o, (float*)d_out, N);
}

// Round 2
// 650.760 us; speedup vs baseline: 1.2043x; 1.2043x over previous
//
#include <hip/hip_runtime.h>
#include <math.h>

#define BN_EPS 1e-5f
constexpr int CAP = 64;  // max neighbors/node incl self-loop; deg~Poisson(16), P(>63)~0

// ---- bf16 helpers (header-independent, round-to-nearest-even) ----
__device__ inline unsigned short f2bf(float f) {
    unsigned u = __float_as_uint(f);
    unsigned r = (u + 0x7fffu + ((u >> 16) & 1u)) >> 16;
    return (unsigned short)r;
}
__device__ inline float2 bf2_to_f2(unsigned int v) {
    float2 r;
    r.x = __uint_as_float(v << 16);
    r.y = __uint_as_float(v & 0xffff0000u);
    return r;
}

// ---------------- CSR build (padded, by dst) ----------------
__global__ __launch_bounds__(256) void k_selfloop(int* __restrict__ col, int* __restrict__ cnt, int N) {
    int i = blockIdx.x * 256 + threadIdx.x;
    if (i < N) { col[(size_t)i * CAP] = i; cnt[i] = 1; }
}

__global__ __launch_bounds__(256) void k_fill(const int* __restrict__ ei, int* __restrict__ col,
                                              int* __restrict__ cnt, int E) {
    int e = blockIdx.x * 256 + threadIdx.x;
    if (e < E) {
        int s = ei[e];
        int d = ei[E + e];
        int pos = atomicAdd(&cnt[d], 1);
        if (pos < CAP) col[(size_t)d * CAP + pos] = s;
    }
}

__global__ __launch_bounds__(256) void k_dinv(const int* __restrict__ cnt, float* __restrict__ dinv, int N) {
    int i = blockIdx.x * 256 + threadIdx.x;
    if (i < N) dinv[i] = rsqrtf((float)cnt[i]);
}

// ---------------- fused GEMM: out = rowscale * relu?( (in@w + bias) folded BN ) ----------------
// block = 256 threads, 128 rows/block (2 rows/thread), 4 col-groups/row.
// OutT = float (fp32 out) or unsigned short (bf16 out).
template <int FIN, int FOUT, bool RELU, bool BN, typename OutT>
__global__ __launch_bounds__(256) void gemm_kernel(
    const float* __restrict__ in, const float* __restrict__ w,
    const float* __restrict__ bias,
    const float* __restrict__ g, const float* __restrict__ beta,
    const float* __restrict__ mm, const float* __restrict__ vv,
    const float* __restrict__ rowscale,
    OutT* __restrict__ out, int N)
{
    constexpr int KT = 32;
    constexpr int COLS = FOUT / 4;
    __shared__ float lw[KT * FOUT];
    __shared__ float cs[FOUT];
    __shared__ float ct[FOUT];

    const int tid = threadIdx.x;
    const int cg = tid & 3;
    const int rr = tid >> 2;
    const int r0 = blockIdx.x * 128 + rr;
    const int r1 = r0 + 64;
    const int r0c = min(r0, N - 1);
    const int r1c = min(r1, N - 1);

    if (tid < FOUT) {
        float s = 1.f, t = 0.f;
        if constexpr (BN) {
            s = g[tid] * rsqrtf(vv[tid] + BN_EPS);
            t = beta[tid] - mm[tid] * s;
        }
        float bb = bias ? bias[tid] : 0.f;
        cs[tid] = s;
        ct[tid] = bb * s + t;
    }

    float acc0[COLS], acc1[COLS];
#pragma unroll
    for (int c = 0; c < COLS; ++c) { acc0[c] = 0.f; acc1[c] = 0.f; }

    const float4* in4_0 = (const float4*)(in + (size_t)r0c * FIN);
    const float4* in4_1 = (const float4*)(in + (size_t)r1c * FIN);

    for (int k0 = 0; k0 < FIN; k0 += KT) {
        __syncthreads();
        const float4* wsrc = (const float4*)(w + (size_t)k0 * FOUT);
        float4* ldst = (float4*)lw;
#pragma unroll
        for (int i = 0; i < KT * FOUT / 4 / 256; ++i)
            ldst[tid + i * 256] = wsrc[tid + i * 256];
        __syncthreads();

#pragma unroll
        for (int kk = 0; kk < KT; kk += 4) {
            float4 a = in4_0[(k0 + kk) >> 2];
            float4 b = in4_1[(k0 + kk) >> 2];
            float av[4] = {a.x, a.y, a.z, a.w};
            float bv[4] = {b.x, b.y, b.z, b.w};
#pragma unroll
            for (int j = 0; j < 4; ++j) {
                const float4* wrow = (const float4*)&lw[(kk + j) * FOUT];
#pragma unroll
                for (int c4 = 0; c4 < COLS / 4; ++c4) {
                    float4 wvv = wrow[c4 * 4 + cg];
                    acc0[c4 * 4 + 0] += av[j] * wvv.x; acc1[c4 * 4 + 0] += bv[j] * wvv.x;
                    acc0[c4 * 4 + 1] += av[j] * wvv.y; acc1[c4 * 4 + 1] += bv[j] * wvv.y;
                    acc0[c4 * 4 + 2] += av[j] * wvv.z; acc1[c4 * 4 + 2] += bv[j] * wvv.z;
                    acc0[c4 * 4 + 3] += av[j] * wvv.w; acc1[c4 * 4 + 3] += bv[j] * wvv.w;
                }
            }
        }
    }

#pragma unroll
    for (int half = 0; half < 2; ++half) {
        const int r = half ? r1 : r0;
        float* acc = half ? acc1 : acc0;
        if (r < N) {
            float sc = rowscale ? rowscale[r] : 1.f;
#pragma unroll
            for (int c4 = 0; c4 < COLS / 4; ++c4) {
                int colb = c4 * 16 + cg * 4;
                float z0 = acc[c4 * 4 + 0] * cs[colb + 0] + ct[colb + 0];
                float z1 = acc[c4 * 4 + 1] * cs[colb + 1] + ct[colb + 1];
                float z2 = acc[c4 * 4 + 2] * cs[colb + 2] + ct[colb + 2];
                float z3 = acc[c4 * 4 + 3] * cs[colb + 3] + ct[colb + 3];
                if constexpr (RELU) { z0 = fmaxf(z0, 0.f); z1 = fmaxf(z1, 0.f); z2 = fmaxf(z2, 0.f); z3 = fmaxf(z3, 0.f); }
                z0 *= sc; z1 *= sc; z2 *= sc; z3 *= sc;
                if constexpr (sizeof(OutT) == 2) {
                    ushort4 zz = { f2bf(z0), f2bf(z1), f2bf(z2), f2bf(z3) };
                    ((ushort4*)((unsigned short*)out + (size_t)r * FOUT))[c4 * 4 + cg] = zz;
                } else {
                    float4 zz = { z0, z1, z2, z3 };
                    ((float4*)((float*)out + (size_t)r * FOUT))[c4 * 4 + cg] = zz;
                }
            }
        }
    }
}

// ---------------- aggregation: hout[i] = dinv[i] * sum_{j in row(i)} hin_bf16[j] ----------------
// hin rows are bf16 (dinv[j] pre-folded by producer epilogue); accumulate fp32; out fp32.
// One wave per node.
template <int F>
__global__ __launch_bounds__(256) void agg_kernel(
    const unsigned short* __restrict__ hin, float* __restrict__ hout,
    const int* __restrict__ col, const int* __restrict__ cnt,
    const float* __restrict__ dinv, int N)
{
    const int wave = (blockIdx.x * 256 + threadIdx.x) >> 6;
    const int lane = threadIdx.x & 63;
    if (wave >= N) return;
    const int n = min(cnt[wave], CAP);
    const int* __restrict__ c = col + (size_t)wave * CAP;

    if constexpr (F == 128) {
        // row = 256B; lane reads one bf16x2 (4B)
        float2 acc = {0.f, 0.f};
        int p = 0;
        for (; p + 4 <= n; p += 4) {
            int j0 = c[p], j1 = c[p + 1], j2 = c[p + 2], j3 = c[p + 3];
            unsigned v0 = ((const unsigned*)(hin + (size_t)j0 * 128))[lane];
            unsigned v1 = ((const unsigned*)(hin + (size_t)j1 * 128))[lane];
            unsigned v2 = ((const unsigned*)(hin + (size_t)j2 * 128))[lane];
            unsigned v3 = ((const unsigned*)(hin + (size_t)j3 * 128))[lane];
            float2 a = bf2_to_f2(v0), b = bf2_to_f2(v1), d2 = bf2_to_f2(v2), e2 = bf2_to_f2(v3);
            acc.x += (a.x + b.x) + (d2.x + e2.x);
            acc.y += (a.y + b.y) + (d2.y + e2.y);
        }
        for (; p < n; ++p) {
            unsigned v = ((const unsigned*)(hin + (size_t)c[p] * 128))[lane];
            float2 a = bf2_to_f2(v);
            acc.x += a.x; acc.y += a.y;
        }
        float d = dinv[wave];
        float2 res = {acc.x * d, acc.y * d};
        ((float2*)(hout + (size_t)wave * 128))[lane] = res;
    } else {
        // row = 128B; half-wave per neighbor: lanes 0-31 take even p, 32-63 odd p.
        const int half = lane >> 5;
        const int li = lane & 31;
        float2 acc = {0.f, 0.f};
        int p = half;
        for (; p + 2 < n; p += 4) {
            int j0 = c[p], j1 = c[p + 2];
            unsigned v0 = ((const unsigned*)(hin + (size_t)j0 * 64))[li];
            unsigned v1 = ((const unsigned*)(hin + (size_t)j1 * 64))[li];
            float2 a = bf2_to_f2(v0), b = bf2_to_f2(v1);
            acc.x += a.x + b.x;
            acc.y += a.y + b.y;
        }
        if (p < n) {
            unsigned v = ((const unsigned*)(hin + (size_t)c[p] * 64))[li];
            float2 a = bf2_to_f2(v);
            acc.x += a.x; acc.y += a.y;
        }
        acc.x += __shfl_xor(acc.x, 32);
        acc.y += __shfl_xor(acc.y, 32);
        if (half == 0) {
            float d = dinv[wave];
            float2 res = {acc.x * d, acc.y * d};
            ((float2*)(hout + (size_t)wave * 64))[li] = res;
        }
    }
}

// ---------------- final: bias3 + BN3 + ReLU + (64x8 GEMM) + log_softmax ----------------
__global__ __launch_bounds__(256) void final_kernel(
    const float* __restrict__ a3,
    const float* __restrict__ b3, const float* __restrict__ g3, const float* __restrict__ beta3,
    const float* __restrict__ m3, const float* __restrict__ v3,
    const float* __restrict__ w_out, const float* __restrict__ b_out,
    float* __restrict__ out, int N)
{
    __shared__ float sw[64 * 8];
    __shared__ float S[64];
    __shared__ float T[64];
    __shared__ float sb[8];
    const int tid = threadIdx.x;
    if (tid < 64) {
        float s = g3[tid] * rsqrtf(v3[tid] + BN_EPS);
        S[tid] = s;
        T[tid] = b3[tid] * s + beta3[tid] - m3[tid] * s;
    }
    if (tid < 8) sb[tid] = b_out[tid];
    sw[tid] = w_out[tid];
    sw[tid + 256] = w_out[tid + 256];
    __syncthreads();

    const int i = blockIdx.x * 256 + tid;
    if (i >= N) return;

    const float4* row = (const float4*)(a3 + (size_t)i * 64);
    float lg[8];
#pragma unroll
    for (int cc = 0; cc < 8; ++cc) lg[cc] = sb[cc];
#pragma unroll
    for (int f4 = 0; f4 < 16; ++f4) {
        float4 av = row[f4];
        float a[4] = {av.x, av.y, av.z, av.w};
#pragma unroll
        for (int j = 0; j < 4; ++j) {
            int f = f4 * 4 + j;
            float z = a[j] * S[f] + T[f];
            z = fmaxf(z, 0.f);
#pragma unroll
            for (int cc = 0; cc < 8; ++cc) lg[cc] += z * sw[f * 8 + cc];
        }
    }
    float mx = lg[0];
#pragma unroll
    for (int cc = 1; cc < 8; ++cc) mx = fmaxf(mx, lg[cc]);
    float sum = 0.f;
#pragma unroll
    for (int cc = 0; cc < 8; ++cc) sum += expf(lg[cc] - mx);
    float lse = logf(sum) + mx;
    float4 o0 = {lg[0] - lse, lg[1] - lse, lg[2] - lse, lg[3] - lse};
    float4 o1 = {lg[4] - lse, lg[5] - lse, lg[6] - lse, lg[7] - lse};
    float4* op = (float4*)(out + (size_t)i * 8);
    op[0] = o0;
    op[1] = o1;
}

extern "C" void kernel_launch(void* const* d_in, const int* in_sizes, int n_in,
                              void* d_out, int out_size, void* d_ws, size_t ws_size,
                              hipStream_t stream) {
    const float* x     = (const float*)d_in[0];
    const int*   ei    = (const int*)d_in[1];
    const float* w_in  = (const float*)d_in[2];
    const float* b_in  = (const float*)d_in[3];
    const float* w1    = (const float*)d_in[4];
    const float* b1    = (const float*)d_in[5];
    const float* w2    = (const float*)d_in[6];
    const float* b2    = (const float*)d_in[7];
    const float* w3    = (const float*)d_in[8];
    const float* b3    = (const float*)d_in[9];
    const float* w_o   = (const float*)d_in[10];
    const float* b_o   = (const float*)d_in[11];
    const float* g1    = (const float*)d_in[12];
    const float* be1   = (const float*)d_in[13];
    const float* m1    = (const float*)d_in[14];
    const float* v1    = (const float*)d_in[15];
    const float* g2    = (const float*)d_in[16];
    const float* be2   = (const float*)d_in[17];
    const float* m2    = (const float*)d_in[18];
    const float* v2    = (const float*)d_in[19];
    const float* g3    = (const float*)d_in[20];
    const float* be3   = (const float*)d_in[21];
    const float* m3    = (const float*)d_in[22];
    const float* v3    = (const float*)d_in[23];

    const int N = in_sizes[0] / 128;
    const int E = in_sizes[1] / 2;

    char* p = (char*)d_ws;
    auto alloc = [&](size_t bytes) {
        void* r = (void*)p;
        p += (bytes + 255) & ~(size_t)255;
        return r;
    };
    int*            cnt  = (int*)alloc((size_t)N * 4);
    float*          dinv = (float*)alloc((size_t)N * 4);
    int*            col  = (int*)alloc((size_t)N * CAP * 4);
    float*          bufA = (float*)alloc((size_t)N * 128 * 4);
    float*          bufB = (float*)alloc((size_t)N * 128 * 4);
    unsigned short* hb   = (unsigned short*)alloc((size_t)N * 128 * 2);  // bf16 h buffer (reused per layer)

    const int gN = (N + 255) / 256;
    const int gE = (E + 255) / 256;
    const int gG = (N + 127) / 128;   // gemm: 128 rows/block
    const int gA = (N + 3) / 4;       // agg: 4 nodes/block (wave per node)

    // CSR build
    k_selfloop<<<gN, 256, 0, stream>>>(col, cnt, N);
    k_fill<<<gE, 256, 0, stream>>>(ei, col, cnt, E);
    k_dinv<<<gN, 256, 0, stream>>>(cnt, dinv, N);

    // h0s = bf16( dinv * relu(x @ w_in + b_in) )               [N,64]  -> hb
    gemm_kernel<128, 64, true, false, unsigned short><<<gG, 256, 0, stream>>>(
        x, w_in, b_in, nullptr, nullptr, nullptr, nullptr, dinv, hb, N);
    // a1 = A_hat @ h0                                          [N,64]  -> bufB (fp32)
    agg_kernel<64><<<gA, 256, 0, stream>>>(hb, bufB, col, cnt, dinv, N);
    // h1s = bf16( dinv * relu(bn1(a1 @ w1 + b1)) )             [N,128] -> hb
    gemm_kernel<64, 128, true, true, unsigned short><<<gG, 256, 0, stream>>>(
        bufB, w1, b1, g1, be1, m1, v1, dinv, hb, N);
    // a2 = A_hat @ h1                                          [N,128] -> bufB (fp32)
    agg_kernel<128><<<gA, 256, 0, stream>>>(hb, bufB, col, cnt, dinv, N);
    // h2 = relu(bn2(a2 @ w2 + b2))   (unscaled, fp32)          [N,128] -> bufA
    gemm_kernel<128, 128, true, true, float><<<gG, 256, 0, stream>>>(
        bufB, w2, b2, g2, be2, m2, v2, nullptr, bufA, N);
    // t3s = bf16( dinv * (h2 @ w3) )                           [N,64]  -> hb
    gemm_kernel<128, 64, false, false, unsigned short><<<gG, 256, 0, stream>>>(
        bufA, w3, nullptr, nullptr, nullptr, nullptr, nullptr, dinv, hb, N);
    // a3 = A_hat @ t3                                          [N,64]  -> bufB (fp32)
    agg_kernel<64><<<gA, 256, 0, stream>>>(hb, bufB, col, cnt, dinv, N);
    // out = log_softmax(relu(bn3(a3 + b3)) @ w_out + b_out)    [N,8]
    final_kernel<<<gN, 256, 0, stream>>>(bufB, b3, g3, be3, m3, v3, w_o, b_o, (float*)d_out, N);
}

// Round 3
// 567.695 us; speedup vs baseline: 1.3806x; 1.1463x over previous
//
#include <hip/hip_runtime.h>
#include <math.h>

#define BN_EPS 1e-5f
constexpr int CAP = 64;   // max neighbors/node incl self-loop; deg~Poisson(16), P(>63)~0
constexpr int BSH = 9;    // dst-bucket shift: 512 nodes / bucket
constexpr int BCAP = 10240; // entries per bucket (avg 8192, sd ~90)

// ---- bf16 helpers (round-to-nearest-even) ----
__device__ inline unsigned short f2bf(float f) {
    unsigned u = __float_as_uint(f);
    unsigned r = (u + 0x7fffu + ((u >> 16) & 1u)) >> 16;
    return (unsigned short)r;
}
__device__ inline float2 bf2_to_f2(unsigned int v) {
    float2 r;
    r.x = __uint_as_float(v << 16);
    r.y = __uint_as_float(v & 0xffff0000u);
    return r;
}

// ---------------- graph build: 2-phase dst-binned counting sort ----------------
__global__ __launch_bounds__(256) void k_zero(int* __restrict__ bcnt, int K) {
    int i = blockIdx.x * 256 + threadIdx.x;
    if (i < K) bcnt[i] = 0;
}

// Phase 1: bin edges by dst>>BSH. Block = 2048 edges; LDS histogram -> one global
// atomic per (block,bucket) -> contiguous append (~10 entries/bucket/block).
__global__ __launch_bounds__(256) void k_bin(const int* __restrict__ ei, int E, int K,
                                             uint2* __restrict__ bins, int* __restrict__ bcnt) {
    __shared__ int hist[256];
    __shared__ int lbase[256];
    const int tid = threadIdx.x;
    const int e0 = blockIdx.x * 2048;
    hist[tid] = 0;
    __syncthreads();

    int s[8], d[8];
    bool m[8];
#pragma unroll
    for (int i = 0; i < 8; ++i) {
        int e = e0 + i * 256 + tid;
        m[i] = e < E;
        s[i] = m[i] ? ei[e] : 0;
        d[i] = m[i] ? ei[E + e] : 0;
        if (m[i]) atomicAdd(&hist[d[i] >> BSH], 1);
    }
    __syncthreads();
    if (tid < K && hist[tid] > 0) lbase[tid] = atomicAdd(&bcnt[tid], hist[tid]);
    __syncthreads();
    hist[tid] = 0;
    __syncthreads();
#pragma unroll
    for (int i = 0; i < 8; ++i) {
        if (m[i]) {
            int b = d[i] >> BSH;
            int pos = lbase[b] + atomicAdd(&hist[b], 1);
            if (pos < BCAP) bins[(size_t)b * BCAP + pos] = make_uint2((unsigned)s[i], (unsigned)d[i]);
        }
    }
}

// Phase 2: one block per bucket. col region (512 nodes x 256B = 128KB) is
// block-exclusive -> single-XCD L2 assembly, full-line writebacks once.
// Fuses self-loop insertion, cnt write, dinv compute.
__global__ __launch_bounds__(1024) void k_place(const uint2* __restrict__ bins,
                                                const int* __restrict__ bcnt,
                                                int* __restrict__ col, int* __restrict__ cnt,
                                                float* __restrict__ dinv, int N) {
    const int b = blockIdx.x;
    const int node0 = b << BSH;
    const int nn = min(1 << BSH, N - node0);
    __shared__ int c2[1 << BSH];
    const int tid = threadIdx.x;
    for (int i = tid; i < nn; i += 1024) {
        c2[i] = 1;                                  // slot 0 = self-loop
        col[(size_t)(node0 + i) * CAP] = node0 + i;
    }
    __syncthreads();
    const int nb = min(bcnt[b], BCAP);
    const uint2* __restrict__ bb = bins + (size_t)b * BCAP;
    for (int i = tid; i < nb; i += 1024) {
        uint2 e = bb[i];
        int pos = atomicAdd(&c2[(int)e.y - node0], 1);
        if (pos < CAP) col[(size_t)e.y * CAP + pos] = (int)e.x;
    }
    __syncthreads();
    for (int i = tid; i < nn; i += 1024) {
        int c = c2[i];
        cnt[node0 + i] = c;
        dinv[node0 + i] = rsqrtf((float)c);
    }
}

// ---------------- fused GEMM: out = rowscale * relu?( (in@w + bias) folded BN ) ----------------
template <int FIN, int FOUT, bool RELU, bool BN, typename OutT>
__global__ __launch_bounds__(256) void gemm_kernel(
    const float* __restrict__ in, const float* __restrict__ w,
    const float* __restrict__ bias,
    const float* __restrict__ g, const float* __restrict__ beta,
    const float* __restrict__ mm, const float* __restrict__ vv,
    const float* __restrict__ rowscale,
    OutT* __restrict__ out, int N)
{
    constexpr int KT = 32;
    constexpr int COLS = FOUT / 4;
    __shared__ float lw[KT * FOUT];
    __shared__ float cs[FOUT];
    __shared__ float ct[FOUT];

    const int tid = threadIdx.x;
    const int cg = tid & 3;
    const int rr = tid >> 2;
    const int r0 = blockIdx.x * 128 + rr;
    const int r1 = r0 + 64;
    const int r0c = min(r0, N - 1);
    const int r1c = min(r1, N - 1);

    if (tid < FOUT) {
        float s = 1.f, t = 0.f;
        if constexpr (BN) {
            s = g[tid] * rsqrtf(vv[tid] + BN_EPS);
            t = beta[tid] - mm[tid] * s;
        }
        float bb = bias ? bias[tid] : 0.f;
        cs[tid] = s;
        ct[tid] = bb * s + t;
    }

    float acc0[COLS], acc1[COLS];
#pragma unroll
    for (int c = 0; c < COLS; ++c) { acc0[c] = 0.f; acc1[c] = 0.f; }

    const float4* in4_0 = (const float4*)(in + (size_t)r0c * FIN);
    const float4* in4_1 = (const float4*)(in + (size_t)r1c * FIN);

    for (int k0 = 0; k0 < FIN; k0 += KT) {
        __syncthreads();
        const float4* wsrc = (const float4*)(w + (size_t)k0 * FOUT);
        float4* ldst = (float4*)lw;
#pragma unroll
        for (int i = 0; i < KT * FOUT / 4 / 256; ++i)
            ldst[tid + i * 256] = wsrc[tid + i * 256];
        __syncthreads();

#pragma unroll
        for (int kk = 0; kk < KT; kk += 4) {
            float4 a = in4_0[(k0 + kk) >> 2];
            float4 b = in4_1[(k0 + kk) >> 2];
            float av[4] = {a.x, a.y, a.z, a.w};
            float bv[4] = {b.x, b.y, b.z, b.w};
#pragma unroll
            for (int j = 0; j < 4; ++j) {
                const float4* wrow = (const float4*)&lw[(kk + j) * FOUT];
#pragma unroll
                for (int c4 = 0; c4 < COLS / 4; ++c4) {
                    float4 wvv = wrow[c4 * 4 + cg];
                    acc0[c4 * 4 + 0] += av[j] * wvv.x; acc1[c4 * 4 + 0] += bv[j] * wvv.x;
                    acc0[c4 * 4 + 1] += av[j] * wvv.y; acc1[c4 * 4 + 1] += bv[j] * wvv.y;
                    acc0[c4 * 4 + 2] += av[j] * wvv.z; acc1[c4 * 4 + 2] += bv[j] * wvv.z;
                    acc0[c4 * 4 + 3] += av[j] * wvv.w; acc1[c4 * 4 + 3] += bv[j] * wvv.w;
                }
            }
        }
    }

#pragma unroll
    for (int half = 0; half < 2; ++half) {
        const int r = half ? r1 : r0;
        float* acc = half ? acc1 : acc0;
        if (r < N) {
            float sc = rowscale ? rowscale[r] : 1.f;
#pragma unroll
            for (int c4 = 0; c4 < COLS / 4; ++c4) {
                int colb = c4 * 16 + cg * 4;
                float z0 = acc[c4 * 4 + 0] * cs[colb + 0] + ct[colb + 0];
                float z1 = acc[c4 * 4 + 1] * cs[colb + 1] + ct[colb + 1];
                float z2 = acc[c4 * 4 + 2] * cs[colb + 2] + ct[colb + 2];
                float z3 = acc[c4 * 4 + 3] * cs[colb + 3] + ct[colb + 3];
                if constexpr (RELU) { z0 = fmaxf(z0, 0.f); z1 = fmaxf(z1, 0.f); z2 = fmaxf(z2, 0.f); z3 = fmaxf(z3, 0.f); }
                z0 *= sc; z1 *= sc; z2 *= sc; z3 *= sc;
                if constexpr (sizeof(OutT) == 2) {
                    ushort4 zz = { f2bf(z0), f2bf(z1), f2bf(z2), f2bf(z3) };
                    ((ushort4*)((unsigned short*)out + (size_t)r * FOUT))[c4 * 4 + cg] = zz;
                } else {
                    float4 zz = { z0, z1, z2, z3 };
                    ((float4*)((float*)out + (size_t)r * FOUT))[c4 * 4 + cg] = zz;
                }
            }
        }
    }
}

// ---------------- aggregation: hout[i] = dinv[i] * sum_{j in row(i)} hin_bf16[j] ----------------
template <int F>
__global__ __launch_bounds__(256) void agg_kernel(
    const unsigned short* __restrict__ hin, float* __restrict__ hout,
    const int* __restrict__ col, const int* __restrict__ cnt,
    const float* __restrict__ dinv, int N)
{
    const int wave = (blockIdx.x * 256 + threadIdx.x) >> 6;
    const int lane = threadIdx.x & 63;
    if (wave >= N) return;
    const int n = min(cnt[wave], CAP);
    const int* __restrict__ c = col + (size_t)wave * CAP;

    if constexpr (F == 128) {
        float2 acc = {0.f, 0.f};
        int p = 0;
        for (; p + 4 <= n; p += 4) {
            int j0 = c[p], j1 = c[p + 1], j2 = c[p + 2], j3 = c[p + 3];
            unsigned v0 = ((const unsigned*)(hin + (size_t)j0 * 128))[lane];
            unsigned v1 = ((const unsigned*)(hin + (size_t)j1 * 128))[lane];
            unsigned v2 = ((const unsigned*)(hin + (size_t)j2 * 128))[lane];
            unsigned v3 = ((const unsigned*)(hin + (size_t)j3 * 128))[lane];
            float2 a = bf2_to_f2(v0), b = bf2_to_f2(v1), d2 = bf2_to_f2(v2), e2 = bf2_to_f2(v3);
            acc.x += (a.x + b.x) + (d2.x + e2.x);
            acc.y += (a.y + b.y) + (d2.y + e2.y);
        }
        for (; p < n; ++p) {
            unsigned v = ((const unsigned*)(hin + (size_t)c[p] * 128))[lane];
            float2 a = bf2_to_f2(v);
            acc.x += a.x; acc.y += a.y;
        }
        float d = dinv[wave];
        float2 res = {acc.x * d, acc.y * d};
        ((float2*)(hout + (size_t)wave * 128))[lane] = res;
    } else {
        const int half = lane >> 5;
        const int li = lane & 31;
        float2 acc = {0.f, 0.f};
        int p = half;
        for (; p + 2 < n; p += 4) {
            int j0 = c[p], j1 = c[p + 2];
            unsigned v0 = ((const unsigned*)(hin + (size_t)j0 * 64))[li];
            unsigned v1 = ((const unsigned*)(hin + (size_t)j1 * 64))[li];
            float2 a = bf2_to_f2(v0), b = bf2_to_f2(v1);
            acc.x += a.x + b.x;
            acc.y += a.y + b.y;
        }
        if (p < n) {
            unsigned v = ((const unsigned*)(hin + (size_t)c[p] * 64))[li];
            float2 a = bf2_to_f2(v);
            acc.x += a.x; acc.y += a.y;
        }
        acc.x += __shfl_xor(acc.x, 32);
        acc.y += __shfl_xor(acc.y, 32);
        if (half == 0) {
            float d = dinv[wave];
            float2 res = {acc.x * d, acc.y * d};
            ((float2*)(hout + (size_t)wave * 64))[li] = res;
        }
    }
}

// ---------------- final: bias3 + BN3 + ReLU + (64x8 GEMM) + log_softmax ----------------
__global__ __launch_bounds__(256) void final_kernel(
    const float* __restrict__ a3,
    const float* __restrict__ b3, const float* __restrict__ g3, const float* __restrict__ beta3,
    const float* __restrict__ m3, const float* __restrict__ v3,
    const float* __restrict__ w_out, const float* __restrict__ b_out,
    float* __restrict__ out, int N)
{
    __shared__ float sw[64 * 8];
    __shared__ float S[64];
    __shared__ float T[64];
    __shared__ float sb[8];
    const int tid = threadIdx.x;
    if (tid < 64) {
        float s = g3[tid] * rsqrtf(v3[tid] + BN_EPS);
        S[tid] = s;
        T[tid] = b3[tid] * s + beta3[tid] - m3[tid] * s;
    }
    if (tid < 8) sb[tid] = b_out[tid];
    sw[tid] = w_out[tid];
    sw[tid + 256] = w_out[tid + 256];
    __syncthreads();

    const int i = blockIdx.x * 256 + tid;
    if (i >= N) return;

    const float4* row = (const float4*)(a3 + (size_t)i * 64);
    float lg[8];
#pragma unroll
    for (int cc = 0; cc < 8; ++cc) lg[cc] = sb[cc];
#pragma unroll
    for (int f4 = 0; f4 < 16; ++f4) {
        float4 av = row[f4];
        float a[4] = {av.x, av.y, av.z, av.w};
#pragma unroll
        for (int j = 0; j < 4; ++j) {
            int f = f4 * 4 + j;
            float z = a[j] * S[f] + T[f];
            z = fmaxf(z, 0.f);
#pragma unroll
            for (int cc = 0; cc < 8; ++cc) lg[cc] += z * sw[f * 8 + cc];
        }
    }
    float mx = lg[0];
#pragma unroll
    for (int cc = 1; cc < 8; ++cc) mx = fmaxf(mx, lg[cc]);
    float sum = 0.f;
#pragma unroll
    for (int cc = 0; cc < 8; ++cc) sum += expf(lg[cc] - mx);
    float lse = logf(sum) + mx;
    float4 o0 = {lg[0] - lse, lg[1] - lse, lg[2] - lse, lg[3] - lse};
    float4 o1 = {lg[4] - lse, lg[5] - lse, lg[6] - lse, lg[7] - lse};
    float4* op = (float4*)(out + (size_t)i * 8);
    op[0] = o0;
    op[1] = o1;
}

extern "C" void kernel_launch(void* const* d_in, const int* in_sizes, int n_in,
                              void* d_out, int out_size, void* d_ws, size_t ws_size,
                              hipStream_t stream) {
    const float* x     = (const float*)d_in[0];
    const int*   ei    = (const int*)d_in[1];
    const float* w_in  = (const float*)d_in[2];
    const float* b_in  = (const float*)d_in[3];
    const float* w1    = (const float*)d_in[4];
    const float* b1    = (const float*)d_in[5];
    const float* w2    = (const float*)d_in[6];
    const float* b2    = (const float*)d_in[7];
    const float* w3    = (const float*)d_in[8];
    const float* b3    = (const float*)d_in[9];
    const float* w_o   = (const float*)d_in[10];
    const float* b_o   = (const float*)d_in[11];
    const float* g1    = (const float*)d_in[12];
    const float* be1   = (const float*)d_in[13];
    const float* m1    = (const float*)d_in[14];
    const float* v1    = (const float*)d_in[15];
    const float* g2    = (const float*)d_in[16];
    const float* be2   = (const float*)d_in[17];
    const float* m2    = (const float*)d_in[18];
    const float* v2    = (const float*)d_in[19];
    const float* g3    = (const float*)d_in[20];
    const float* be3   = (const float*)d_in[21];
    const float* m3    = (const float*)d_in[22];
    const float* v3    = (const float*)d_in[23];

    const int N = in_sizes[0] / 128;
    const int E = in_sizes[1] / 2;
    const int K = (N + (1 << BSH) - 1) >> BSH;   // dst buckets

    char* p = (char*)d_ws;
    auto alloc = [&](size_t bytes) {
        void* r = (void*)p;
        p += (bytes + 255) & ~(size_t)255;
        return r;
    };
    int*            cnt  = (int*)alloc((size_t)N * 4);
    float*          dinv = (float*)alloc((size_t)N * 4);
    int*            bcnt = (int*)alloc(256 * 4);
    int*            col  = (int*)alloc((size_t)N * CAP * 4);
    float*          bufA = (float*)alloc((size_t)N * 128 * 4);   // also aliased as bins (16.1MB < 51.2MB)
    float*          bufB = (float*)alloc((size_t)N * 128 * 4);
    unsigned short* hb   = (unsigned short*)alloc((size_t)N * 128 * 2);
    uint2*          bins = (uint2*)bufA;  // consumed by k_place before bufA's first GEMM use

    const int gN  = (N + 255) / 256;
    const int gB1 = (E + 2047) / 2048;   // k_bin: 2048 edges/block
    const int gG  = (N + 127) / 128;     // gemm: 128 rows/block
    const int gA  = (N + 3) / 4;         // agg: 4 nodes/block (wave per node)

    // graph build: binned counting sort
    k_zero<<<1, 256, 0, stream>>>(bcnt, K);
    k_bin<<<gB1, 256, 0, stream>>>(ei, E, K, bins, bcnt);
    k_place<<<K, 1024, 0, stream>>>(bins, bcnt, col, cnt, dinv, N);

    // h0s = bf16( dinv * relu(x @ w_in + b_in) )               [N,64]  -> hb
    gemm_kernel<128, 64, true, false, unsigned short><<<gG, 256, 0, stream>>>(
        x, w_in, b_in, nullptr, nullptr, nullptr, nullptr, dinv, hb, N);
    // a1 = A_hat @ h0                                          [N,64]  -> bufB (fp32)
    agg_kernel<64><<<gA, 256, 0, stream>>>(hb, bufB, col, cnt, dinv, N);
    // h1s = bf16( dinv * relu(bn1(a1 @ w1 + b1)) )             [N,128] -> hb
    gemm_kernel<64, 128, true, true, unsigned short><<<gG, 256, 0, stream>>>(
        bufB, w1, b1, g1, be1, m1, v1, dinv, hb, N);
    // a2 = A_hat @ h1                                          [N,128] -> bufB (fp32)
    agg_kernel<128><<<gA, 256, 0, stream>>>(hb, bufB, col, cnt, dinv, N);
    // h2 = relu(bn2(a2 @ w2 + b2))   (unscaled, fp32)          [N,128] -> bufA
    gemm_kernel<128, 128, true, true, float><<<gG, 256, 0, stream>>>(
        bufB, w2, b2, g2, be2, m2, v2, nullptr, bufA, N);
    // t3s = bf16( dinv * (h2 @ w3) )                           [N,64]  -> hb
    gemm_kernel<128, 64, false, false, unsigned short><<<gG, 256, 0, stream>>>(
        bufA, w3, nullptr, nullptr, nullptr, nullptr, nullptr, dinv, hb, N);
    // a3 = A_hat @ t3                                          [N,64]  -> bufB (fp32)
    agg_kernel<64><<<gA, 256, 0, stream>>>(hb, bufB, col, cnt, dinv, N);
    // out = log_softmax(relu(bn3(a3 + b3)) @ w_out + b_out)    [N,8]
    final_kernel<<<gN, 256, 0, stream>>>(bufB, b3, g3, be3, m3, v3, w_o, b_o, (float*)d_out, N);
}

// Round 4
// 549.127 us; speedup vs baseline: 1.4272x; 1.0338x over previous
//
#include <hip/hip_runtime.h>
#include <math.h>

#define BN_EPS 1e-5f
constexpr int CAP = 64;     // max neighbors/node incl self-loop; deg~Poisson(16), P(>63)~0
constexpr int BSH = 9;      // dst-bucket shift: 512 nodes / bucket
constexpr int BCAP = 10240; // entries per bucket (avg 8192, sd ~90; +22 sigma)

// ---- bf16 helpers (round-to-nearest-even) ----
__device__ inline unsigned short f2bf(float f) {
    unsigned u = __float_as_uint(f);
    unsigned r = (u + 0x7fffu + ((u >> 16) & 1u)) >> 16;
    return (unsigned short)r;
}
__device__ inline unsigned pack2bf(float x, float y) {
    return (unsigned)f2bf(x) | ((unsigned)f2bf(y) << 16);
}
__device__ inline float2 bf2_to_f2(unsigned int v) {
    float2 r;
    r.x = __uint_as_float(v << 16);
    r.y = __uint_as_float(v & 0xffff0000u);
    return r;
}

// ---------------- graph build: 2-phase dst-binned counting sort ----------------
__global__ __launch_bounds__(256) void k_zero(int* __restrict__ bcnt, int K) {
    int i = blockIdx.x * 256 + threadIdx.x;
    if (i < K) bcnt[i] = 0;
}

__global__ __launch_bounds__(256) void k_bin(const int* __restrict__ ei, int E, int K,
                                             uint2* __restrict__ bins, int* __restrict__ bcnt) {
    __shared__ int hist[256];
    __shared__ int lbase[256];
    const int tid = threadIdx.x;
    const int e0 = blockIdx.x * 2048;
    hist[tid] = 0;
    __syncthreads();

    int s[8], d[8];
    bool m[8];
#pragma unroll
    for (int i = 0; i < 8; ++i) {
        int e = e0 + i * 256 + tid;
        m[i] = e < E;
        s[i] = m[i] ? ei[e] : 0;
        d[i] = m[i] ? ei[E + e] : 0;
        if (m[i]) atomicAdd(&hist[d[i] >> BSH], 1);
    }
    __syncthreads();
    if (tid < K && hist[tid] > 0) lbase[tid] = atomicAdd(&bcnt[tid], hist[tid]);
    __syncthreads();
    hist[tid] = 0;
    __syncthreads();
#pragma unroll
    for (int i = 0; i < 8; ++i) {
        if (m[i]) {
            int b = d[i] >> BSH;
            int pos = lbase[b] + atomicAdd(&hist[b], 1);
            if (pos < BCAP) bins[(size_t)b * BCAP + pos] = make_uint2((unsigned)s[i], (unsigned)d[i]);
        }
    }
}

__global__ __launch_bounds__(1024) void k_place(const uint2* __restrict__ bins,
                                                const int* __restrict__ bcnt,
                                                int* __restrict__ col, int* __restrict__ cnt,
                                                float* __restrict__ dinv, int N) {
    const int b = blockIdx.x;
    const int node0 = b << BSH;
    const int nn = min(1 << BSH, N - node0);
    __shared__ int c2[1 << BSH];
    const int tid = threadIdx.x;
    for (int i = tid; i < nn; i += 1024) {
        c2[i] = 1;
        col[(size_t)(node0 + i) * CAP] = node0 + i;
    }
    __syncthreads();
    const int nb = min(bcnt[b], BCAP);
    const uint2* __restrict__ bb = bins + (size_t)b * BCAP;
    for (int i = tid; i < nb; i += 1024) {
        uint2 e = bb[i];
        int pos = atomicAdd(&c2[(int)e.y - node0], 1);
        if (pos < CAP) col[(size_t)e.y * CAP + pos] = (int)e.x;
    }
    __syncthreads();
    for (int i = tid; i < nn; i += 1024) {
        int c = c2[i];
        cnt[node0 + i] = c;
        dinv[node0 + i] = rsqrtf((float)c);
    }
}

// ---------------- generic GEMM: out_bf16 = rowscale * relu?( BN?(in@w + bias) ) ----------------
// Full W resident in LDS (fp32, <=32KB), ONE barrier, barrier-free full-K loop.
// 256 thr, 128 rows/block (2 rows/thread), cols = c4*16+cg*4+j.
template <int FIN, int FOUT, bool RELU, bool BN, typename InT>
__global__ __launch_bounds__(256) void gemm_kernel(
    const InT* __restrict__ in, const float* __restrict__ w,
    const float* __restrict__ bias,
    const float* __restrict__ g, const float* __restrict__ beta,
    const float* __restrict__ mm, const float* __restrict__ vv,
    const float* __restrict__ rowscale,
    unsigned short* __restrict__ out, int N)
{
    constexpr int COLS = FOUT / 4;
    __shared__ float lw[FIN * FOUT];
    __shared__ float cs[FOUT];
    __shared__ float ct[FOUT];

    const int tid = threadIdx.x;
    const int cg = tid & 3;
    const int rr = tid >> 2;
    const int r0 = blockIdx.x * 128 + rr;
    const int r1 = r0 + 64;
    const int r0c = min(r0, N - 1);
    const int r1c = min(r1, N - 1);

    {
        const float4* ws = (const float4*)w;
        float4* ld = (float4*)lw;
#pragma unroll
        for (int i = 0; i < FIN * FOUT / 1024; ++i)
            ld[tid + i * 256] = ws[tid + i * 256];
    }
    if (tid < FOUT) {
        float s = 1.f, t = 0.f;
        if constexpr (BN) {
            s = g[tid] * rsqrtf(vv[tid] + BN_EPS);
            t = beta[tid] - mm[tid] * s;
        }
        float bb = bias ? bias[tid] : 0.f;
        cs[tid] = s;
        ct[tid] = bb * s + t;
    }
    __syncthreads();

    float acc0[COLS], acc1[COLS];
#pragma unroll
    for (int c = 0; c < COLS; ++c) { acc0[c] = 0.f; acc1[c] = 0.f; }

    if constexpr (sizeof(InT) == 2) {
        const uint4* rp0 = (const uint4*)(in + (size_t)r0c * FIN);
        const uint4* rp1 = (const uint4*)(in + (size_t)r1c * FIN);
#pragma unroll 4
        for (int kc = 0; kc < FIN / 8; ++kc) {
            uint4 q0 = rp0[kc];
            uint4 q1 = rp1[kc];
            float2 a01 = bf2_to_f2(q0.x), a23 = bf2_to_f2(q0.y), a45 = bf2_to_f2(q0.z), a67 = bf2_to_f2(q0.w);
            float2 b01 = bf2_to_f2(q1.x), b23 = bf2_to_f2(q1.y), b45 = bf2_to_f2(q1.z), b67 = bf2_to_f2(q1.w);
            float av[8] = {a01.x, a01.y, a23.x, a23.y, a45.x, a45.y, a67.x, a67.y};
            float bv[8] = {b01.x, b01.y, b23.x, b23.y, b45.x, b45.y, b67.x, b67.y};
#pragma unroll
            for (int j = 0; j < 8; ++j) {
                const float4* wrow = (const float4*)&lw[(kc * 8 + j) * FOUT];
#pragma unroll
                for (int c4 = 0; c4 < COLS / 4; ++c4) {
                    float4 wv = wrow[c4 * 4 + cg];
                    acc0[c4 * 4 + 0] += av[j] * wv.x; acc1[c4 * 4 + 0] += bv[j] * wv.x;
                    acc0[c4 * 4 + 1] += av[j] * wv.y; acc1[c4 * 4 + 1] += bv[j] * wv.y;
                    acc0[c4 * 4 + 2] += av[j] * wv.z; acc1[c4 * 4 + 2] += bv[j] * wv.z;
                    acc0[c4 * 4 + 3] += av[j] * wv.w; acc1[c4 * 4 + 3] += bv[j] * wv.w;
                }
            }
        }
    } else {
        const float4* rp0 = (const float4*)(in + (size_t)r0c * FIN);
        const float4* rp1 = (const float4*)(in + (size_t)r1c * FIN);
#pragma unroll 4
        for (int kc = 0; kc < FIN / 4; ++kc) {
            float4 a4 = rp0[kc];
            float4 b4 = rp1[kc];
            float av[4] = {a4.x, a4.y, a4.z, a4.w};
            float bv[4] = {b4.x, b4.y, b4.z, b4.w};
#pragma unroll
            for (int j = 0; j < 4; ++j) {
                const float4* wrow = (const float4*)&lw[(kc * 4 + j) * FOUT];
#pragma unroll
                for (int c4 = 0; c4 < COLS / 4; ++c4) {
                    float4 wv = wrow[c4 * 4 + cg];
                    acc0[c4 * 4 + 0] += av[j] * wv.x; acc1[c4 * 4 + 0] += bv[j] * wv.x;
                    acc0[c4 * 4 + 1] += av[j] * wv.y; acc1[c4 * 4 + 1] += bv[j] * wv.y;
                    acc0[c4 * 4 + 2] += av[j] * wv.z; acc1[c4 * 4 + 2] += bv[j] * wv.z;
                    acc0[c4 * 4 + 3] += av[j] * wv.w; acc1[c4 * 4 + 3] += bv[j] * wv.w;
                }
            }
        }
    }

#pragma unroll
    for (int half = 0; half < 2; ++half) {
        const int r = half ? r1 : r0;
        float* acc = half ? acc1 : acc0;
        if (r < N) {
            float sc = rowscale ? rowscale[r] : 1.f;
#pragma unroll
            for (int c4 = 0; c4 < COLS / 4; ++c4) {
                int colb = c4 * 16 + cg * 4;
                float z0 = acc[c4 * 4 + 0] * cs[colb + 0] + ct[colb + 0];
                float z1 = acc[c4 * 4 + 1] * cs[colb + 1] + ct[colb + 1];
                float z2 = acc[c4 * 4 + 2] * cs[colb + 2] + ct[colb + 2];
                float z3 = acc[c4 * 4 + 3] * cs[colb + 3] + ct[colb + 3];
                if constexpr (RELU) { z0 = fmaxf(z0, 0.f); z1 = fmaxf(z1, 0.f); z2 = fmaxf(z2, 0.f); z3 = fmaxf(z3, 0.f); }
                ushort4 zz = { f2bf(z0 * sc), f2bf(z1 * sc), f2bf(z2 * sc), f2bf(z3 * sc) };
                ((ushort4*)(out + (size_t)r * FOUT))[c4 * 4 + cg] = zz;
            }
        }
    }
}

// ---------------- fused layer-3: t3 = dinv * ( relu(bn2(a2@w2 + b2)) @ w3 ) ----------------
// a2 bf16 [N,128] -> t3 bf16 [N,64]. w2 staged in 2 fp32 K-tiles (LDS reused for w3);
// h2 round-trips through a bank-conflict-free bf16 LDS tile (row stride 132).
__global__ __launch_bounds__(256) void gemm23_kernel(
    const unsigned short* __restrict__ in, const float* __restrict__ w2,
    const float* __restrict__ b2,
    const float* __restrict__ g2, const float* __restrict__ beta2,
    const float* __restrict__ m2, const float* __restrict__ v2,
    const float* __restrict__ w3, const float* __restrict__ rowscale,
    unsigned short* __restrict__ out, int N)
{
    constexpr int LH = 132;  // lh2 row stride (ushorts): 264B -> per-row bank offset 2
    __shared__ float lsw[64 * 128];          // w2 K-tile, later w3 (128x64) — both 8192 floats
    __shared__ unsigned short lh2[128 * LH]; // h2 tile bf16
    __shared__ float cs[128];
    __shared__ float ct[128];

    const int tid = threadIdx.x;
    const int cg = tid & 3;
    const int rr = tid >> 2;
    const int r0 = blockIdx.x * 128 + rr;
    const int r1 = r0 + 64;
    const int r0c = min(r0, N - 1);
    const int r1c = min(r1, N - 1);

    if (tid < 128) {
        float s = g2[tid] * rsqrtf(v2[tid] + BN_EPS);
        cs[tid] = s;
        ct[tid] = b2[tid] * s + beta2[tid] - m2[tid] * s;
    }

    float acc0[32], acc1[32];
#pragma unroll
    for (int c = 0; c < 32; ++c) { acc0[c] = 0.f; acc1[c] = 0.f; }

    const uint4* rp0 = (const uint4*)(in + (size_t)r0c * 128);
    const uint4* rp1 = (const uint4*)(in + (size_t)r1c * 128);

    // ---- phase A: z2 = a2 @ w2  (two 64-K tiles) ----
    for (int kt = 0; kt < 2; ++kt) {
        __syncthreads();
        {
            const float4* ws = (const float4*)(w2 + (size_t)kt * 64 * 128);
            float4* ld = (float4*)lsw;
#pragma unroll
            for (int i = 0; i < 8; ++i) ld[tid + i * 256] = ws[tid + i * 256];
        }
        __syncthreads();
#pragma unroll 4
        for (int kc = 0; kc < 8; ++kc) {
            uint4 q0 = rp0[kt * 8 + kc];
            uint4 q1 = rp1[kt * 8 + kc];
            float2 a01 = bf2_to_f2(q0.x), a23 = bf2_to_f2(q0.y), a45 = bf2_to_f2(q0.z), a67 = bf2_to_f2(q0.w);
            float2 b01 = bf2_to_f2(q1.x), b23 = bf2_to_f2(q1.y), b45 = bf2_to_f2(q1.z), b67 = bf2_to_f2(q1.w);
            float av[8] = {a01.x, a01.y, a23.x, a23.y, a45.x, a45.y, a67.x, a67.y};
            float bv[8] = {b01.x, b01.y, b23.x, b23.y, b45.x, b45.y, b67.x, b67.y};
#pragma unroll
            for (int j = 0; j < 8; ++j) {
                const float4* wrow = (const float4*)&lsw[(kc * 8 + j) * 128];
#pragma unroll
                for (int c4 = 0; c4 < 8; ++c4) {
                    float4 wv = wrow[c4 * 4 + cg];
                    acc0[c4 * 4 + 0] += av[j] * wv.x; acc1[c4 * 4 + 0] += bv[j] * wv.x;
                    acc0[c4 * 4 + 1] += av[j] * wv.y; acc1[c4 * 4 + 1] += bv[j] * wv.y;
                    acc0[c4 * 4 + 2] += av[j] * wv.z; acc1[c4 * 4 + 2] += bv[j] * wv.z;
                    acc0[c4 * 4 + 3] += av[j] * wv.w; acc1[c4 * 4 + 3] += bv[j] * wv.w;
                }
            }
        }
    }

    // ---- h2 = relu(z2*cs+ct) -> LDS bf16 tile ----
#pragma unroll
    for (int half = 0; half < 2; ++half) {
        const int rl = rr + half * 64;
        float* acc = half ? acc1 : acc0;
#pragma unroll
        for (int c4 = 0; c4 < 8; ++c4) {
            int colb = c4 * 16 + cg * 4;
            float z0 = fmaxf(acc[c4 * 4 + 0] * cs[colb + 0] + ct[colb + 0], 0.f);
            float z1 = fmaxf(acc[c4 * 4 + 1] * cs[colb + 1] + ct[colb + 1], 0.f);
            float z2 = fmaxf(acc[c4 * 4 + 2] * cs[colb + 2] + ct[colb + 2], 0.f);
            float z3 = fmaxf(acc[c4 * 4 + 3] * cs[colb + 3] + ct[colb + 3], 0.f);
            ushort4 zz = { f2bf(z0), f2bf(z1), f2bf(z2), f2bf(z3) };
            *(ushort4*)&lh2[rl * LH + colb] = zz;
        }
    }
    __syncthreads();   // lh2 complete; lsw free
    {
        const float4* ws = (const float4*)w3;
        float4* ld = (float4*)lsw;
#pragma unroll
        for (int i = 0; i < 8; ++i) ld[tid + i * 256] = ws[tid + i * 256];
    }
    __syncthreads();

    // ---- phase B: t3 = h2 @ w3 (from LDS) ----
    float t0[16], t1[16];
#pragma unroll
    for (int c = 0; c < 16; ++c) { t0[c] = 0.f; t1[c] = 0.f; }

#pragma unroll 8
    for (int kc = 0; kc < 32; ++kc) {
        ushort4 h0 = *(const ushort4*)&lh2[rr * LH + kc * 4];
        ushort4 h1 = *(const ushort4*)&lh2[(rr + 64) * LH + kc * 4];
        float2 a01 = bf2_to_f2((unsigned)h0.x | ((unsigned)h0.y << 16));
        float2 a23 = bf2_to_f2((unsigned)h0.z | ((unsigned)h0.w << 16));
        float2 b01 = bf2_to_f2((unsigned)h1.x | ((unsigned)h1.y << 16));
        float2 b23 = bf2_to_f2((unsigned)h1.z | ((unsigned)h1.w << 16));
        float av[4] = {a01.x, a01.y, a23.x, a23.y};
        float bv[4] = {b01.x, b01.y, b23.x, b23.y};
#pragma unroll
        for (int j = 0; j < 4; ++j) {
            const float4* wrow = (const float4*)&lsw[(kc * 4 + j) * 64];
#pragma unroll
            for (int c4 = 0; c4 < 4; ++c4) {
                float4 wv = wrow[c4 * 4 + cg];
                t0[c4 * 4 + 0] += av[j] * wv.x; t1[c4 * 4 + 0] += bv[j] * wv.x;
                t0[c4 * 4 + 1] += av[j] * wv.y; t1[c4 * 4 + 1] += bv[j] * wv.y;
                t0[c4 * 4 + 2] += av[j] * wv.z; t1[c4 * 4 + 2] += bv[j] * wv.z;
                t0[c4 * 4 + 3] += av[j] * wv.w; t1[c4 * 4 + 3] += bv[j] * wv.w;
            }
        }
    }

#pragma unroll
    for (int half = 0; half < 2; ++half) {
        const int r = half ? r1 : r0;
        float* acc = half ? t1 : t0;
        if (r < N) {
            float sc = rowscale[r];
#pragma unroll
            for (int c4 = 0; c4 < 4; ++c4) {
                ushort4 zz = { f2bf(acc[c4 * 4 + 0] * sc), f2bf(acc[c4 * 4 + 1] * sc),
                               f2bf(acc[c4 * 4 + 2] * sc), f2bf(acc[c4 * 4 + 3] * sc) };
                ((ushort4*)(out + (size_t)r * 64))[c4 * 4 + cg] = zz;
            }
        }
    }
}

// ---------------- aggregation: hout_bf16[i] = dinv[i] * sum_{j in row(i)} hin_bf16[j] ----------------
template <int F>
__global__ __launch_bounds__(256) void agg_kernel(
    const unsigned short* __restrict__ hin, unsigned short* __restrict__ hout,
    const int* __restrict__ col, const int* __restrict__ cnt,
    const float* __restrict__ dinv, int N)
{
    const int wave = (blockIdx.x * 256 + threadIdx.x) >> 6;
    const int lane = threadIdx.x & 63;
    if (wave >= N) return;
    const int n = min(cnt[wave], CAP);
    const int* __restrict__ c = col + (size_t)wave * CAP;

    if constexpr (F == 128) {
        float2 acc = {0.f, 0.f};
        int p = 0;
        for (; p + 4 <= n; p += 4) {
            int j0 = c[p], j1 = c[p + 1], j2 = c[p + 2], j3 = c[p + 3];
            unsigned v0 = ((const unsigned*)(hin + (size_t)j0 * 128))[lane];
            unsigned v1 = ((const unsigned*)(hin + (size_t)j1 * 128))[lane];
            unsigned v2 = ((const unsigned*)(hin + (size_t)j2 * 128))[lane];
            unsigned v3 = ((const unsigned*)(hin + (size_t)j3 * 128))[lane];
            float2 a = bf2_to_f2(v0), b = bf2_to_f2(v1), d2 = bf2_to_f2(v2), e2 = bf2_to_f2(v3);
            acc.x += (a.x + b.x) + (d2.x + e2.x);
            acc.y += (a.y + b.y) + (d2.y + e2.y);
        }
        for (; p < n; ++p) {
            unsigned v = ((const unsigned*)(hin + (size_t)c[p] * 128))[lane];
            float2 a = bf2_to_f2(v);
            acc.x += a.x; acc.y += a.y;
        }
        float d = dinv[wave];
        ((unsigned*)(hout + (size_t)wave * 128))[lane] = pack2bf(acc.x * d, acc.y * d);
    } else {
        const int half = lane >> 5;
        const int li = lane & 31;
        float2 acc = {0.f, 0.f};
        int p = half;
        for (; p + 2 < n; p += 4) {
            int j0 = c[p], j1 = c[p + 2];
            unsigned v0 = ((const unsigned*)(hin + (size_t)j0 * 64))[li];
            unsigned v1 = ((const unsigned*)(hin + (size_t)j1 * 64))[li];
            float2 a = bf2_to_f2(v0), b = bf2_to_f2(v1);
            acc.x += a.x + b.x;
            acc.y += a.y + b.y;
        }
        if (p < n) {
            unsigned v = ((const unsigned*)(hin + (size_t)c[p] * 64))[li];
            float2 a = bf2_to_f2(v);
            acc.x += a.x; acc.y += a.y;
        }
        acc.x += __shfl_xor(acc.x, 32);
        acc.y += __shfl_xor(acc.y, 32);
        if (half == 0) {
            float d = dinv[wave];
            ((unsigned*)(hout + (size_t)wave * 64))[li] = pack2bf(acc.x * d, acc.y * d);
        }
    }
}

// ---------------- final: bias3 + BN3 + ReLU + (64x8 GEMM) + log_softmax ----------------
__global__ __launch_bounds__(256) void final_kernel(
    const unsigned short* __restrict__ a3,
    const float* __restrict__ b3, const float* __restrict__ g3, const float* __restrict__ beta3,
    const float* __restrict__ m3, const float* __restrict__ v3,
    const float* __restrict__ w_out, const float* __restrict__ b_out,
    float* __restrict__ out, int N)
{
    __shared__ float sw[64 * 8];
    __shared__ float S[64];
    __shared__ float T[64];
    __shared__ float sb[8];
    const int tid = threadIdx.x;
    if (tid < 64) {
        float s = g3[tid] * rsqrtf(v3[tid] + BN_EPS);
        S[tid] = s;
        T[tid] = b3[tid] * s + beta3[tid] - m3[tid] * s;
    }
    if (tid < 8) sb[tid] = b_out[tid];
    sw[tid] = w_out[tid];
    sw[tid + 256] = w_out[tid + 256];
    __syncthreads();

    const int i = blockIdx.x * 256 + tid;
    if (i >= N) return;

    const uint4* row = (const uint4*)(a3 + (size_t)i * 64);
    float lg[8];
#pragma unroll
    for (int cc = 0; cc < 8; ++cc) lg[cc] = sb[cc];
#pragma unroll
    for (int q = 0; q < 8; ++q) {
        uint4 qv = row[q];
        float2 p01 = bf2_to_f2(qv.x), p23 = bf2_to_f2(qv.y), p45 = bf2_to_f2(qv.z), p67 = bf2_to_f2(qv.w);
        float a[8] = {p01.x, p01.y, p23.x, p23.y, p45.x, p45.y, p67.x, p67.y};
#pragma unroll
        for (int j = 0; j < 8; ++j) {
            int f = q * 8 + j;
            float z = fmaxf(a[j] * S[f] + T[f], 0.f);
#pragma unroll
            for (int cc = 0; cc < 8; ++cc) lg[cc] += z * sw[f * 8 + cc];
        }
    }
    float mx = lg[0];
#pragma unroll
    for (int cc = 1; cc < 8; ++cc) mx = fmaxf(mx, lg[cc]);
    float sum = 0.f;
#pragma unroll
    for (int cc = 0; cc < 8; ++cc) sum += expf(lg[cc] - mx);
    float lse = logf(sum) + mx;
    float4 o0 = {lg[0] - lse, lg[1] - lse, lg[2] - lse, lg[3] - lse};
    float4 o1 = {lg[4] - lse, lg[5] - lse, lg[6] - lse, lg[7] - lse};
    float4* op = (float4*)(out + (size_t)i * 8);
    op[0] = o0;
    op[1] = o1;
}

extern "C" void kernel_launch(void* const* d_in, const int* in_sizes, int n_in,
                              void* d_out, int out_size, void* d_ws, size_t ws_size,
                              hipStream_t stream) {
    const float* x     = (const float*)d_in[0];
    const int*   ei    = (const int*)d_in[1];
    const float* w_in  = (const float*)d_in[2];
    const float* b_in  = (const float*)d_in[3];
    const float* w1    = (const float*)d_in[4];
    const float* b1    = (const float*)d_in[5];
    const float* w2    = (const float*)d_in[6];
    const float* b2    = (const float*)d_in[7];
    const float* w3    = (const float*)d_in[8];
    const float* b3    = (const float*)d_in[9];
    const float* w_o   = (const float*)d_in[10];
    const float* b_o   = (const float*)d_in[11];
    const float* g1    = (const float*)d_in[12];
    const float* be1   = (const float*)d_in[13];
    const float* m1    = (const float*)d_in[14];
    const float* v1    = (const float*)d_in[15];
    const float* g2    = (const float*)d_in[16];
    const float* be2   = (const float*)d_in[17];
    const float* m2    = (const float*)d_in[18];
    const float* v2    = (const float*)d_in[19];
    const float* g3    = (const float*)d_in[20];
    const float* be3   = (const float*)d_in[21];
    const float* m3    = (const float*)d_in[22];
    const float* v3    = (const float*)d_in[23];

    const int N = in_sizes[0] / 128;
    const int E = in_sizes[1] / 2;
    const int K = (N + (1 << BSH) - 1) >> BSH;

    char* p = (char*)d_ws;
    auto alloc = [&](size_t bytes) {
        void* r = (void*)p;
        p += (bytes + 255) & ~(size_t)255;
        return r;
    };
    int*            cnt  = (int*)alloc((size_t)N * 4);
    float*          dinv = (float*)alloc((size_t)N * 4);
    int*            bcnt = (int*)alloc(256 * 4);
    int*            col  = (int*)alloc((size_t)N * CAP * 4);
    uint2*          bins = (uint2*)alloc((size_t)K * BCAP * 8);
    unsigned short* hbA  = (unsigned short*)alloc((size_t)N * 128 * 2);
    unsigned short* hbB  = (unsigned short*)alloc((size_t)N * 128 * 2);

    const int gN  = (N + 255) / 256;
    const int gB1 = (E + 2047) / 2048;
    const int gG  = (N + 127) / 128;
    const int gA  = (N + 3) / 4;

    // graph build
    k_zero<<<1, 256, 0, stream>>>(bcnt, K);
    k_bin<<<gB1, 256, 0, stream>>>(ei, E, K, bins, bcnt);
    k_place<<<K, 1024, 0, stream>>>(bins, bcnt, col, cnt, dinv, N);

    // h0s = bf16( dinv * relu(x @ w_in + b_in) )               [N,64]  -> hbA
    gemm_kernel<128, 64, true, false, float><<<gG, 256, 0, stream>>>(
        x, w_in, b_in, nullptr, nullptr, nullptr, nullptr, dinv, hbA, N);
    // a1 = A_hat @ h0                                          [N,64]  -> hbB
    agg_kernel<64><<<gA, 256, 0, stream>>>(hbA, hbB, col, cnt, dinv, N);
    // h1s = bf16( dinv * relu(bn1(a1 @ w1 + b1)) )             [N,128] -> hbA
    gemm_kernel<64, 128, true, true, unsigned short><<<gG, 256, 0, stream>>>(
        hbB, w1, b1, g1, be1, m1, v1, dinv, hbA, N);
    // a2 = A_hat @ h1                                          [N,128] -> hbB
    agg_kernel<128><<<gA, 256, 0, stream>>>(hbA, hbB, col, cnt, dinv, N);
    // t3s = bf16( dinv * (relu(bn2(a2@w2+b2)) @ w3) )          [N,64]  -> hbA  (fused)
    gemm23_kernel<<<gG, 256, 0, stream>>>(
        hbB, w2, b2, g2, be2, m2, v2, w3, dinv, hbA, N);
    // a3 = A_hat @ t3                                          [N,64]  -> hbB
    agg_kernel<64><<<gA, 256, 0, stream>>>(hbA, hbB, col, cnt, dinv, N);
    // out = log_softmax(relu(bn3(a3 + b3)) @ w_out + b_out)    [N,8]
    final_kernel<<<gN, 256, 0, stream>>>(hbB, b3, g3, be3, m3, v3, w_o, b_o, (float*)d_out, N);
}

// Round 5
// 449.238 us; speedup vs baseline: 1.7446x; 1.2224x over previous
//
#include <hip/hip_runtime.h>
#include <math.h>

#define BN_EPS 1e-5f
constexpr int CAP = 64;     // max neighbors/node incl self-loop; deg~Poisson(16), P(>63)~0
constexpr int BSH = 9;      // dst-bucket shift: 512 nodes / bucket
constexpr int BCAP = 10240; // entries per bucket (avg 8192, sd ~90; +22 sigma)

typedef __attribute__((ext_vector_type(8))) short bf16x8;
typedef __attribute__((ext_vector_type(4))) float f32x4;

// ---- bf16 helpers (round-to-nearest-even) ----
__device__ inline unsigned short f2bf(float f) {
    unsigned u = __float_as_uint(f);
    unsigned r = (u + 0x7fffu + ((u >> 16) & 1u)) >> 16;
    return (unsigned short)r;
}
__device__ inline unsigned pack2bf(float x, float y) {
    return (unsigned)f2bf(x) | ((unsigned)f2bf(y) << 16);
}
__device__ inline float2 bf2_to_f2(unsigned int v) {
    float2 r;
    r.x = __uint_as_float(v << 16);
    r.y = __uint_as_float(v & 0xffff0000u);
    return r;
}

// ---------------- graph build: 2-phase dst-binned counting sort ----------------
__global__ __launch_bounds__(256) void k_zero(int* __restrict__ bcnt, int K) {
    int i = blockIdx.x * 256 + threadIdx.x;
    if (i < K) bcnt[i] = 0;
}

__global__ __launch_bounds__(256) void k_bin(const int* __restrict__ ei, int E, int K,
                                             uint2* __restrict__ bins, int* __restrict__ bcnt) {
    __shared__ int hist[256];
    __shared__ int lbase[256];
    const int tid = threadIdx.x;
    const int e0 = blockIdx.x * 2048;
    hist[tid] = 0;
    __syncthreads();

    int s[8], d[8];
    bool m[8];
#pragma unroll
    for (int i = 0; i < 8; ++i) {
        int e = e0 + i * 256 + tid;
        m[i] = e < E;
        s[i] = m[i] ? ei[e] : 0;
        d[i] = m[i] ? ei[E + e] : 0;
        if (m[i]) atomicAdd(&hist[d[i] >> BSH], 1);
    }
    __syncthreads();
    if (tid < K && hist[tid] > 0) lbase[tid] = atomicAdd(&bcnt[tid], hist[tid]);
    __syncthreads();
    hist[tid] = 0;
    __syncthreads();
#pragma unroll
    for (int i = 0; i < 8; ++i) {
        if (m[i]) {
            int b = d[i] >> BSH;
            int pos = lbase[b] + atomicAdd(&hist[b], 1);
            if (pos < BCAP) bins[(size_t)b * BCAP + pos] = make_uint2((unsigned)s[i], (unsigned)d[i]);
        }
    }
}

__global__ __launch_bounds__(1024) void k_place(const uint2* __restrict__ bins,
                                                const int* __restrict__ bcnt,
                                                int* __restrict__ col, int* __restrict__ cnt,
                                                float* __restrict__ dinv, int N) {
    const int b = blockIdx.x;
    const int node0 = b << BSH;
    const int nn = min(1 << BSH, N - node0);
    __shared__ int c2[1 << BSH];
    const int tid = threadIdx.x;
    for (int i = tid; i < nn; i += 1024) {
        c2[i] = 1;
        col[(size_t)(node0 + i) * CAP] = node0 + i;
    }
    __syncthreads();
    const int nb = min(bcnt[b], BCAP);
    const uint2* __restrict__ bb = bins + (size_t)b * BCAP;
    for (int i = tid; i < nb; i += 1024) {
        uint2 e = bb[i];
        int pos = atomicAdd(&c2[(int)e.y - node0], 1);
        if (pos < CAP) col[(size_t)e.y * CAP + pos] = (int)e.x;
    }
    __syncthreads();
    for (int i = tid; i < nn; i += 1024) {
        int c = c2[i];
        cnt[node0 + i] = c;
        dinv[node0 + i] = rsqrtf((float)c);
    }
}

// ---------------- MFMA GEMM: out_bf16 = rowscale * relu?( BN?(in @ w + bias) ) ----------------
// 256 thr = 4 waves, 64 rows/block (16 rows/wave). mfma_f32_16x16x32_bf16.
// A-frag: A[m=lane&15][k=quad*8+j]  -> direct global uint4 load (no LDS for A).
// B-frag: W^T staged in LDS fragment-linear: addr = ((ks*NT+nt)*64+lane)*8 shorts
//         -> ds_read_b128 at lane*16B, conflict-free.
// C/D:    col=lane&15, row=quad*4+reg -> epilogue in-register, per-wave LDS
//         transpose tile -> coalesced uint4 global stores.
template <int FIN, int FOUT, bool RELU, bool BN, typename InT>
__global__ __launch_bounds__(256) void mfma_gemm(
    const InT* __restrict__ in, const float* __restrict__ w,
    const float* __restrict__ bias,
    const float* __restrict__ g, const float* __restrict__ beta,
    const float* __restrict__ mm, const float* __restrict__ vv,
    const float* __restrict__ rowscale,
    unsigned short* __restrict__ out, int N)
{
    constexpr int KS = FIN / 32;   // K-steps
    constexpr int NT = FOUT / 16;  // N-tiles per wave
    __shared__ unsigned short lwB[FIN * FOUT];       // fragment-linear bf16 W
    __shared__ unsigned short otile[4 * 16 * FOUT];  // per-wave epilogue transpose
    __shared__ float cs[FOUT], ct[FOUT];

    const int tid = threadIdx.x;

    // repack W[FIN][FOUT] fp32 -> bf16 fragment-linear (one-time)
    for (int idx = tid; idx < FIN * FOUT; idx += 256) {
        int k = idx / FOUT;
        int n = idx - k * FOUT;
        int ks = k >> 5, q = (k >> 3) & 3, j = k & 7;
        lwB[(((size_t)(ks * NT + (n >> 4))) * 64 + q * 16 + (n & 15)) * 8 + j] = f2bf(w[idx]);
    }
    if (tid < FOUT) {
        float s = 1.f, t = 0.f;
        if constexpr (BN) {
            s = g[tid] * rsqrtf(vv[tid] + BN_EPS);
            t = beta[tid] - mm[tid] * s;
        }
        float bb = bias ? bias[tid] : 0.f;
        cs[tid] = s;
        ct[tid] = bb * s + t;
    }
    __syncthreads();

    const int wid = tid >> 6, lane = tid & 63;
    const int q = lane >> 4, m16 = lane & 15;
    const int rowbase = blockIdx.x * 64 + wid * 16;
    const int rowc = min(rowbase + m16, N - 1);

    f32x4 acc[NT];
#pragma unroll
    for (int nt = 0; nt < NT; ++nt) acc[nt] = (f32x4){0.f, 0.f, 0.f, 0.f};

#pragma unroll
    for (int ks = 0; ks < KS; ++ks) {
        bf16x8 af;
        if constexpr (sizeof(InT) == 2) {
            af = *(const bf16x8*)((const unsigned short*)in + (size_t)rowc * FIN + ks * 32 + q * 8);
        } else {
            const float* ap = (const float*)in + (size_t)rowc * FIN + ks * 32 + q * 8;
            float4 a0 = *(const float4*)ap;
            float4 a1 = *(const float4*)(ap + 4);
            af[0] = (short)f2bf(a0.x); af[1] = (short)f2bf(a0.y);
            af[2] = (short)f2bf(a0.z); af[3] = (short)f2bf(a0.w);
            af[4] = (short)f2bf(a1.x); af[5] = (short)f2bf(a1.y);
            af[6] = (short)f2bf(a1.z); af[7] = (short)f2bf(a1.w);
        }
#pragma unroll
        for (int nt = 0; nt < NT; ++nt) {
            bf16x8 bfr = *(const bf16x8*)&lwB[((size_t)(ks * NT + nt) * 64 + lane) * 8];
            acc[nt] = __builtin_amdgcn_mfma_f32_16x16x32_bf16(af, bfr, acc[nt], 0, 0, 0);
        }
    }

    // epilogue: BN/ReLU/rowscale in-register, transpose via per-wave LDS tile
    unsigned short* ot = otile + wid * 16 * FOUT;
    float rs[4];
#pragma unroll
    for (int r = 0; r < 4; ++r) {
        int gr = rowbase + q * 4 + r;
        rs[r] = rowscale ? rowscale[min(gr, N - 1)] : 1.f;
    }
#pragma unroll
    for (int nt = 0; nt < NT; ++nt) {
        int c = nt * 16 + m16;
        float s = cs[c], t = ct[c];
#pragma unroll
        for (int r = 0; r < 4; ++r) {
            float z = acc[nt][r] * s + t;
            if constexpr (RELU) z = fmaxf(z, 0.f);
            ot[(q * 4 + r) * FOUT + c] = f2bf(z * rs[r]);
        }
    }
    // per-wave private tile: compiler inserts lgkm waits; no block barrier needed
    constexpr int CH = FOUT / 8;
#pragma unroll
    for (int idx = lane; idx < 16 * CH; idx += 64) {
        int rrow = idx / CH, cc = idx - rrow * CH;
        int gr = rowbase + rrow;
        if (gr < N)
            *(uint4*)(out + (size_t)gr * FOUT + cc * 8) = *(const uint4*)&ot[rrow * FOUT + cc * 8];
    }
}

// ---------------- aggregation: hout_bf16[i] = dinv[i] * sum_{j in row(i)} hin_bf16[j] ----------------
template <int F>
__global__ __launch_bounds__(256) void agg_kernel(
    const unsigned short* __restrict__ hin, unsigned short* __restrict__ hout,
    const int* __restrict__ col, const int* __restrict__ cnt,
    const float* __restrict__ dinv, int N)
{
    const int wave = (blockIdx.x * 256 + threadIdx.x) >> 6;
    const int lane = threadIdx.x & 63;
    if (wave >= N) return;
    const int n = min(cnt[wave], CAP);
    const int* __restrict__ c = col + (size_t)wave * CAP;

    if constexpr (F == 128) {
        float2 acc = {0.f, 0.f};
        int p = 0;
        for (; p + 4 <= n; p += 4) {
            int j0 = c[p], j1 = c[p + 1], j2 = c[p + 2], j3 = c[p + 3];
            unsigned v0 = ((const unsigned*)(hin + (size_t)j0 * 128))[lane];
            unsigned v1 = ((const unsigned*)(hin + (size_t)j1 * 128))[lane];
            unsigned v2 = ((const unsigned*)(hin + (size_t)j2 * 128))[lane];
            unsigned v3 = ((const unsigned*)(hin + (size_t)j3 * 128))[lane];
            float2 a = bf2_to_f2(v0), b = bf2_to_f2(v1), d2 = bf2_to_f2(v2), e2 = bf2_to_f2(v3);
            acc.x += (a.x + b.x) + (d2.x + e2.x);
            acc.y += (a.y + b.y) + (d2.y + e2.y);
        }
        for (; p < n; ++p) {
            unsigned v = ((const unsigned*)(hin + (size_t)c[p] * 128))[lane];
            float2 a = bf2_to_f2(v);
            acc.x += a.x; acc.y += a.y;
        }
        float d = dinv[wave];
        ((unsigned*)(hout + (size_t)wave * 128))[lane] = pack2bf(acc.x * d, acc.y * d);
    } else {
        const int half = lane >> 5;
        const int li = lane & 31;
        float2 acc = {0.f, 0.f};
        int p = half;
        for (; p + 2 < n; p += 4) {
            int j0 = c[p], j1 = c[p + 2];
            unsigned v0 = ((const unsigned*)(hin + (size_t)j0 * 64))[li];
            unsigned v1 = ((const unsigned*)(hin + (size_t)j1 * 64))[li];
            float2 a = bf2_to_f2(v0), b = bf2_to_f2(v1);
            acc.x += a.x + b.x;
            acc.y += a.y + b.y;
        }
        if (p < n) {
            unsigned v = ((const unsigned*)(hin + (size_t)c[p] * 64))[li];
            float2 a = bf2_to_f2(v);
            acc.x += a.x; acc.y += a.y;
        }
        acc.x += __shfl_xor(acc.x, 32);
        acc.y += __shfl_xor(acc.y, 32);
        if (half == 0) {
            float d = dinv[wave];
            ((unsigned*)(hout + (size_t)wave * 64))[li] = pack2bf(acc.x * d, acc.y * d);
        }
    }
}

// ---------------- final: bias3 + BN3 + ReLU + (64x8 GEMM) + log_softmax ----------------
__global__ __launch_bounds__(256) void final_kernel(
    const unsigned short* __restrict__ a3,
    const float* __restrict__ b3, const float* __restrict__ g3, const float* __restrict__ beta3,
    const float* __restrict__ m3, const float* __restrict__ v3,
    const float* __restrict__ w_out, const float* __restrict__ b_out,
    float* __restrict__ out, int N)
{
    __shared__ float sw[64 * 8];
    __shared__ float S[64];
    __shared__ float T[64];
    __shared__ float sb[8];
    const int tid = threadIdx.x;
    if (tid < 64) {
        float s = g3[tid] * rsqrtf(v3[tid] + BN_EPS);
        S[tid] = s;
        T[tid] = b3[tid] * s + beta3[tid] - m3[tid] * s;
    }
    if (tid < 8) sb[tid] = b_out[tid];
    sw[tid] = w_out[tid];
    sw[tid + 256] = w_out[tid + 256];
    __syncthreads();

    const int i = blockIdx.x * 256 + tid;
    if (i >= N) return;

    const uint4* row = (const uint4*)(a3 + (size_t)i * 64);
    float lg[8];
#pragma unroll
    for (int cc = 0; cc < 8; ++cc) lg[cc] = sb[cc];
#pragma unroll
    for (int qq = 0; qq < 8; ++qq) {
        uint4 qv = row[qq];
        float2 p01 = bf2_to_f2(qv.x), p23 = bf2_to_f2(qv.y), p45 = bf2_to_f2(qv.z), p67 = bf2_to_f2(qv.w);
        float a[8] = {p01.x, p01.y, p23.x, p23.y, p45.x, p45.y, p67.x, p67.y};
#pragma unroll
        for (int j = 0; j < 8; ++j) {
            int f = qq * 8 + j;
            float z = fmaxf(a[j] * S[f] + T[f], 0.f);
#pragma unroll
            for (int cc = 0; cc < 8; ++cc) lg[cc] += z * sw[f * 8 + cc];
        }
    }
    float mx = lg[0];
#pragma unroll
    for (int cc = 1; cc < 8; ++cc) mx = fmaxf(mx, lg[cc]);
    float sum = 0.f;
#pragma unroll
    for (int cc = 0; cc < 8; ++cc) sum += expf(lg[cc] - mx);
    float lse = logf(sum) + mx;
    float4 o0 = {lg[0] - lse, lg[1] - lse, lg[2] - lse, lg[3] - lse};
    float4 o1 = {lg[4] - lse, lg[5] - lse, lg[6] - lse, lg[7] - lse};
    float4* op = (float4*)(out + (size_t)i * 8);
    op[0] = o0;
    op[1] = o1;
}

extern "C" void kernel_launch(void* const* d_in, const int* in_sizes, int n_in,
                              void* d_out, int out_size, void* d_ws, size_t ws_size,
                              hipStream_t stream) {
    const float* x     = (const float*)d_in[0];
    const int*   ei    = (const int*)d_in[1];
    const float* w_in  = (const float*)d_in[2];
    const float* b_in  = (const float*)d_in[3];
    const float* w1    = (const float*)d_in[4];
    const float* b1    = (const float*)d_in[5];
    const float* w2    = (const float*)d_in[6];
    const float* b2    = (const float*)d_in[7];
    const float* w3    = (const float*)d_in[8];
    const float* b3    = (const float*)d_in[9];
    const float* w_o   = (const float*)d_in[10];
    const float* b_o   = (const float*)d_in[11];
    const float* g1    = (const float*)d_in[12];
    const float* be1   = (const float*)d_in[13];
    const float* m1    = (const float*)d_in[14];
    const float* v1    = (const float*)d_in[15];
    const float* g2    = (const float*)d_in[16];
    const float* be2   = (const float*)d_in[17];
    const float* m2    = (const float*)d_in[18];
    const float* v2    = (const float*)d_in[19];
    const float* g3    = (const float*)d_in[20];
    const float* be3   = (const float*)d_in[21];
    const float* m3    = (const float*)d_in[22];
    const float* v3    = (const float*)d_in[23];

    const int N = in_sizes[0] / 128;
    const int E = in_sizes[1] / 2;
    const int K = (N + (1 << BSH) - 1) >> BSH;

    char* p = (char*)d_ws;
    auto alloc = [&](size_t bytes) {
        void* r = (void*)p;
        p += (bytes + 255) & ~(size_t)255;
        return r;
    };
    int*            cnt  = (int*)alloc((size_t)N * 4);
    float*          dinv = (float*)alloc((size_t)N * 4);
    int*            bcnt = (int*)alloc(256 * 4);
    int*            col  = (int*)alloc((size_t)N * CAP * 4);
    uint2*          bins = (uint2*)alloc((size_t)K * BCAP * 8);
    unsigned short* hbA  = (unsigned short*)alloc((size_t)N * 128 * 2);
    unsigned short* hbB  = (unsigned short*)alloc((size_t)N * 128 * 2);
    unsigned short* hbC  = (unsigned short*)alloc((size_t)N * 128 * 2);

    const int gN  = (N + 255) / 256;
    const int gB1 = (E + 2047) / 2048;
    const int gM  = (N + 63) / 64;    // mfma gemm: 64 rows/block
    const int gA  = (N + 3) / 4;      // agg: 4 nodes/block (wave per node)

    // graph build
    k_zero<<<1, 256, 0, stream>>>(bcnt, K);
    k_bin<<<gB1, 256, 0, stream>>>(ei, E, K, bins, bcnt);
    k_place<<<K, 1024, 0, stream>>>(bins, bcnt, col, cnt, dinv, N);

    // h0s = bf16( dinv * relu(x @ w_in + b_in) )               [N,64]  -> hbA
    mfma_gemm<128, 64, true, false, float><<<gM, 256, 0, stream>>>(
        x, w_in, b_in, nullptr, nullptr, nullptr, nullptr, dinv, hbA, N);
    // a1 = A_hat @ h0                                          [N,64]  -> hbB
    agg_kernel<64><<<gA, 256, 0, stream>>>(hbA, hbB, col, cnt, dinv, N);
    // h1s = bf16( dinv * relu(bn1(a1 @ w1 + b1)) )             [N,128] -> hbA
    mfma_gemm<64, 128, true, true, unsigned short><<<gM, 256, 0, stream>>>(
        hbB, w1, b1, g1, be1, m1, v1, dinv, hbA, N);
    // a2 = A_hat @ h1                                          [N,128] -> hbB
    agg_kernel<128><<<gA, 256, 0, stream>>>(hbA, hbB, col, cnt, dinv, N);
    // h2 = relu(bn2(a2 @ w2 + b2))                             [N,128] -> hbC
    mfma_gemm<128, 128, true, true, unsigned short><<<gM, 256, 0, stream>>>(
        hbB, w2, b2, g2, be2, m2, v2, nullptr, hbC, N);
    // t3s = bf16( dinv * (h2 @ w3) )                           [N,64]  -> hbA
    mfma_gemm<128, 64, false, false, unsigned short><<<gM, 256, 0, stream>>>(
        hbC, w3, nullptr, nullptr, nullptr, nullptr, nullptr, dinv, hbA, N);
    // a3 = A_hat @ t3                                          [N,64]  -> hbB
    agg_kernel<64><<<gA, 256, 0, stream>>>(hbA, hbB, col, cnt, dinv, N);
    // out = log_softmax(relu(bn3(a3 + b3)) @ w_out + b_out)    [N,8]
    final_kernel<<<gN, 256, 0, stream>>>(hbB, b3, g3, be3, m3, v3, w_o, b_o, (float*)d_out, N);
}

// Round 6
// 378.762 us; speedup vs baseline: 2.0692x; 1.1861x over previous
//
#include <hip/hip_runtime.h>
#include <math.h>

#define BN_EPS 1e-5f
constexpr int CAP = 64;     // max neighbors/node incl self-loop; deg~Poisson(16), P(>63)~0
constexpr int BSH = 9;      // dst-bucket shift: 512 nodes / bucket
constexpr int BCAP = 10240; // entries per bucket (avg 8192, sd ~90; +22 sigma)

typedef __attribute__((ext_vector_type(8))) short bf16x8;
typedef __attribute__((ext_vector_type(4))) float f32x4;

// ---- bf16 helpers (round-to-nearest-even) ----
__device__ inline unsigned short f2bf(float f) {
    unsigned u = __float_as_uint(f);
    unsigned r = (u + 0x7fffu + ((u >> 16) & 1u)) >> 16;
    return (unsigned short)r;
}
__device__ inline float2 bf2_to_f2(unsigned int v) {
    float2 r;
    r.x = __uint_as_float(v << 16);
    r.y = __uint_as_float(v & 0xffff0000u);
    return r;
}
// accumulate 8 bf16 (uint4) into float[8]
__device__ inline void addv(float* a, uint4 v) {
    float2 x0 = bf2_to_f2(v.x), x1 = bf2_to_f2(v.y), x2 = bf2_to_f2(v.z), x3 = bf2_to_f2(v.w);
    a[0] += x0.x; a[1] += x0.y; a[2] += x1.x; a[3] += x1.y;
    a[4] += x2.x; a[5] += x2.y; a[6] += x3.x; a[7] += x3.y;
}

// ---------------- graph build: 2-phase dst-binned counting sort ----------------
__global__ __launch_bounds__(256) void k_zero(int* __restrict__ bcnt, int K) {
    int i = blockIdx.x * 256 + threadIdx.x;
    if (i < K) bcnt[i] = 0;
}

__global__ __launch_bounds__(256) void k_bin(const int* __restrict__ ei, int E, int K,
                                             uint2* __restrict__ bins, int* __restrict__ bcnt) {
    __shared__ int hist[256];
    __shared__ int lbase[256];
    const int tid = threadIdx.x;
    const int e0 = blockIdx.x * 2048;
    hist[tid] = 0;
    __syncthreads();

    int s[8], d[8];
    bool m[8];
#pragma unroll
    for (int i = 0; i < 8; ++i) {
        int e = e0 + i * 256 + tid;
        m[i] = e < E;
        s[i] = m[i] ? ei[e] : 0;
        d[i] = m[i] ? ei[E + e] : 0;
        if (m[i]) atomicAdd(&hist[d[i] >> BSH], 1);
    }
    __syncthreads();
    if (tid < K && hist[tid] > 0) lbase[tid] = atomicAdd(&bcnt[tid], hist[tid]);
    __syncthreads();
    hist[tid] = 0;
    __syncthreads();
#pragma unroll
    for (int i = 0; i < 8; ++i) {
        if (m[i]) {
            int b = d[i] >> BSH;
            int pos = lbase[b] + atomicAdd(&hist[b], 1);
            if (pos < BCAP) bins[(size_t)b * BCAP + pos] = make_uint2((unsigned)s[i], (unsigned)d[i]);
        }
    }
}

__global__ __launch_bounds__(1024) void k_place(const uint2* __restrict__ bins,
                                                const int* __restrict__ bcnt,
                                                int* __restrict__ col, int* __restrict__ cnt,
                                                float* __restrict__ dinv, int N) {
    const int b = blockIdx.x;
    const int node0 = b << BSH;
    const int nn = min(1 << BSH, N - node0);
    __shared__ int c2[1 << BSH];
    const int tid = threadIdx.x;
    for (int i = tid; i < nn; i += 1024) {
        c2[i] = 1;
        col[(size_t)(node0 + i) * CAP] = node0 + i;
    }
    __syncthreads();
    const int nb = min(bcnt[b], BCAP);
    const uint2* __restrict__ bb = bins + (size_t)b * BCAP;
    for (int i = tid; i < nb; i += 1024) {
        uint2 e = bb[i];
        int pos = atomicAdd(&c2[(int)e.y - node0], 1);
        if (pos < CAP) col[(size_t)e.y * CAP + pos] = (int)e.x;
    }
    __syncthreads();
    for (int i = tid; i < nn; i += 1024) {
        int c = c2[i];
        cnt[node0 + i] = c;
        dinv[node0 + i] = rsqrtf((float)c);
    }
}

// ---------------- weight repack: fp32 [FIN][FOUT] -> bf16 fragment-linear ----------------
// frag addr: (((k>>5)*NT + (n>>4))*64 + ((k>>3)&3)*16 + (n&15))*8 + (k&7)
// (identical formula as R5's in-kernel repack — HW-verified)
__global__ __launch_bounds__(256) void k_repack(
    const float* __restrict__ w_in, const float* __restrict__ w1,
    const float* __restrict__ w2, const float* __restrict__ w3,
    unsigned short* __restrict__ f_in, unsigned short* __restrict__ f1,
    unsigned short* __restrict__ f2, unsigned short* __restrict__ f3)
{
    int idx = blockIdx.x * 256 + threadIdx.x;  // 0..40959
    const float* src;
    unsigned short* dst;
    int FOUT, local;
    if (idx < 8192)       { src = w_in; dst = f_in; FOUT = 64;  local = idx; }
    else if (idx < 16384) { src = w1;   dst = f1;   FOUT = 128; local = idx - 8192; }
    else if (idx < 32768) { src = w2;   dst = f2;   FOUT = 128; local = idx - 16384; }
    else                  { src = w3;   dst = f3;   FOUT = 64;  local = idx - 32768; }
    int k = local / FOUT, n = local % FOUT;
    int NT = FOUT >> 4;
    dst[((((k >> 5) * NT + (n >> 4)) * 64) + ((k >> 3) & 3) * 16 + (n & 15)) * 8 + (k & 7)] = f2bf(src[local]);
}

// ---------------- layer 0: h0 = bf16( dinv * relu(x @ w_in + b_in) ) ----------------
// 256 thr = 4 waves, 64 rows/block, 16 rows/wave. B-frags direct from global (L2).
__global__ __launch_bounds__(256) void mfma_gemm0(
    const float* __restrict__ in, const unsigned short* __restrict__ wfrag,
    const float* __restrict__ bias, const float* __restrict__ rowscale,
    unsigned short* __restrict__ out, int N)
{
    constexpr int FIN = 128, FOUT = 64, KS = 4, NT = 4, OST = 72;
    __shared__ unsigned short otile[4 * 16 * OST];
    __shared__ float ct[FOUT];
    const int tid = threadIdx.x;
    if (tid < FOUT) ct[tid] = bias[tid];
    __syncthreads();

    const int wid = tid >> 6, lane = tid & 63;
    const int q = lane >> 4, m = lane & 15;
    const int rowbase = blockIdx.x * 64 + wid * 16;
    const int rowc = min(rowbase + m, N - 1);
    const bf16x8* __restrict__ wf = (const bf16x8*)wfrag;

    f32x4 accm[NT];
#pragma unroll
    for (int nt = 0; nt < NT; ++nt) accm[nt] = (f32x4){0.f, 0.f, 0.f, 0.f};

#pragma unroll
    for (int ks = 0; ks < KS; ++ks) {
        const float* ap = in + (size_t)rowc * FIN + ks * 32 + q * 8;
        float4 a0 = *(const float4*)ap;
        float4 a1 = *(const float4*)(ap + 4);
        bf16x8 af;
        af[0] = (short)f2bf(a0.x); af[1] = (short)f2bf(a0.y);
        af[2] = (short)f2bf(a0.z); af[3] = (short)f2bf(a0.w);
        af[4] = (short)f2bf(a1.x); af[5] = (short)f2bf(a1.y);
        af[6] = (short)f2bf(a1.z); af[7] = (short)f2bf(a1.w);
#pragma unroll
        for (int nt = 0; nt < NT; ++nt)
            accm[nt] = __builtin_amdgcn_mfma_f32_16x16x32_bf16(af, wf[(ks * NT + nt) * 64 + lane], accm[nt], 0, 0, 0);
    }

    unsigned short* ot = otile + wid * 16 * OST;
    float rs[4];
#pragma unroll
    for (int r = 0; r < 4; ++r) rs[r] = rowscale[min(rowbase + q * 4 + r, N - 1)];
#pragma unroll
    for (int nt = 0; nt < NT; ++nt) {
        int c = nt * 16 + m;
        float t = ct[c];
#pragma unroll
        for (int r = 0; r < 4; ++r) {
            float z = fmaxf(accm[nt][r] + t, 0.f);
            ot[(q * 4 + r) * OST + c] = f2bf(z * rs[r]);
        }
    }
#pragma unroll
    for (int idx = lane; idx < 16 * (FOUT / 8); idx += 64) {
        int rrow = idx >> 3, cc = idx & 7;
        int gr = rowbase + rrow;
        if (gr < N)
            *(uint4*)(out + (size_t)gr * FOUT + cc * 8) = *(const uint4*)&ot[rrow * OST + cc * 8];
    }
}

// ---------------- layer 1: h1 = bf16( dinv * relu(bn1( (A_hat@h0) @ w1 + b1 )) ) ----------------
// Gather-in-fragment: 4 lanes per node (lane=q*16+m -> node m, chunks c≡q mod 4).
// Lane's fp32 acc == MFMA A-frag elements A[m][ks*32+q*8..+8] directly.
__global__ __launch_bounds__(256) void agg_mfma1(
    const unsigned short* __restrict__ hin, const unsigned short* __restrict__ wfrag,
    const float* __restrict__ bias, const float* __restrict__ g, const float* __restrict__ beta,
    const float* __restrict__ mm, const float* __restrict__ vv,
    const int* __restrict__ col, const int* __restrict__ cnt, const float* __restrict__ dinv,
    unsigned short* __restrict__ out, int N)
{
    constexpr int FIN = 64, FOUT = 128, KS = 2, NT = 8, OST = 136;
    __shared__ unsigned short otile[4 * 16 * OST];
    __shared__ float cs[FOUT], ct[FOUT];
    const int tid = threadIdx.x;
    if (tid < FOUT) {
        float s = g[tid] * rsqrtf(vv[tid] + BN_EPS);
        cs[tid] = s;
        ct[tid] = bias[tid] * s + beta[tid] - mm[tid] * s;
    }
    __syncthreads();

    const int wid = tid >> 6, lane = tid & 63;
    const int q = lane >> 4, m = lane & 15;
    const int rowbase = blockIdx.x * 64 + wid * 16;
    const int node = rowbase + m;
    const int nodec = min(node, N - 1);
    const int n = (node < N) ? min(cnt[node], CAP) : 0;
    const int* __restrict__ c = col + (size_t)nodec * CAP;

    float acc[KS][8];
#pragma unroll
    for (int i = 0; i < KS; ++i)
#pragma unroll
        for (int e = 0; e < 8; ++e) acc[i][e] = 0.f;

    int p = 0;
    for (; p + 2 <= n; p += 2) {
        const unsigned short* r0 = hin + (size_t)c[p] * FIN + q * 8;
        const unsigned short* r1 = hin + (size_t)c[p + 1] * FIN + q * 8;
        uint4 v00 = *(const uint4*)r0, v01 = *(const uint4*)(r0 + 32);
        uint4 v10 = *(const uint4*)r1, v11 = *(const uint4*)(r1 + 32);
        addv(acc[0], v00); addv(acc[1], v01);
        addv(acc[0], v10); addv(acc[1], v11);
    }
    if (p < n) {
        const unsigned short* r0 = hin + (size_t)c[p] * FIN + q * 8;
        addv(acc[0], *(const uint4*)r0);
        addv(acc[1], *(const uint4*)(r0 + 32));
    }

    const float di = dinv[nodec];
    bf16x8 af[KS];
#pragma unroll
    for (int i = 0; i < KS; ++i)
#pragma unroll
        for (int e = 0; e < 8; ++e) af[i][e] = (short)f2bf(acc[i][e] * di);

    f32x4 accm[NT];
#pragma unroll
    for (int nt = 0; nt < NT; ++nt) accm[nt] = (f32x4){0.f, 0.f, 0.f, 0.f};
    const bf16x8* __restrict__ wf = (const bf16x8*)wfrag;
#pragma unroll
    for (int ks = 0; ks < KS; ++ks)
#pragma unroll
        for (int nt = 0; nt < NT; ++nt)
            accm[nt] = __builtin_amdgcn_mfma_f32_16x16x32_bf16(af[ks], wf[(ks * NT + nt) * 64 + lane], accm[nt], 0, 0, 0);

    unsigned short* ot = otile + wid * 16 * OST;
    float rs[4];
#pragma unroll
    for (int r = 0; r < 4; ++r) rs[r] = dinv[min(rowbase + q * 4 + r, N - 1)];
#pragma unroll
    for (int nt = 0; nt < NT; ++nt) {
        int cc = nt * 16 + m;
        float s = cs[cc], t = ct[cc];
#pragma unroll
        for (int r = 0; r < 4; ++r) {
            float z = fmaxf(accm[nt][r] * s + t, 0.f);
            ot[(q * 4 + r) * OST + cc] = f2bf(z * rs[r]);
        }
    }
#pragma unroll
    for (int idx = lane; idx < 16 * (FOUT / 8); idx += 64) {
        int rrow = idx >> 4, cc = idx & 15;
        int gr = rowbase + rrow;
        if (gr < N)
            *(uint4*)(out + (size_t)gr * FOUT + cc * 8) = *(const uint4*)&ot[rrow * OST + cc * 8];
    }
}

// ---------------- layers 2+3 fused: t3 = bf16( dinv * ( relu(bn2((A_hat@h1)@w2+b2)) @ w3 ) ) ----------------
__global__ __launch_bounds__(256) void agg_mfma23(
    const unsigned short* __restrict__ hin, const unsigned short* __restrict__ w2f,
    const float* __restrict__ b2, const float* __restrict__ g2, const float* __restrict__ beta2,
    const float* __restrict__ m2, const float* __restrict__ v2,
    const unsigned short* __restrict__ w3f,
    const int* __restrict__ col, const int* __restrict__ cnt, const float* __restrict__ dinv,
    unsigned short* __restrict__ out, int N)
{
    constexpr int FIN = 128, KS = 4, NT1 = 8, NT2 = 4, OST = 136, OST2 = 72;
    __shared__ unsigned short otile[4 * 16 * OST];
    __shared__ float cs[128], ct[128];
    const int tid = threadIdx.x;
    if (tid < 128) {
        float s = g2[tid] * rsqrtf(v2[tid] + BN_EPS);
        cs[tid] = s;
        ct[tid] = b2[tid] * s + beta2[tid] - m2[tid] * s;
    }
    __syncthreads();

    const int wid = tid >> 6, lane = tid & 63;
    const int q = lane >> 4, m = lane & 15;
    const int rowbase = blockIdx.x * 64 + wid * 16;
    const int node = rowbase + m;
    const int nodec = min(node, N - 1);
    const int n = (node < N) ? min(cnt[node], CAP) : 0;
    const int* __restrict__ c = col + (size_t)nodec * CAP;

    float acc[KS][8];
#pragma unroll
    for (int i = 0; i < KS; ++i)
#pragma unroll
        for (int e = 0; e < 8; ++e) acc[i][e] = 0.f;

    int p = 0;
    for (; p + 2 <= n; p += 2) {
        const unsigned short* r0 = hin + (size_t)c[p] * FIN + q * 8;
        const unsigned short* r1 = hin + (size_t)c[p + 1] * FIN + q * 8;
#pragma unroll
        for (int i = 0; i < KS; ++i) addv(acc[i], *(const uint4*)(r0 + i * 32));
#pragma unroll
        for (int i = 0; i < KS; ++i) addv(acc[i], *(const uint4*)(r1 + i * 32));
    }
    if (p < n) {
        const unsigned short* r0 = hin + (size_t)c[p] * FIN + q * 8;
#pragma unroll
        for (int i = 0; i < KS; ++i) addv(acc[i], *(const uint4*)(r0 + i * 32));
    }

    const float di = dinv[nodec];
    bf16x8 af[KS];
#pragma unroll
    for (int i = 0; i < KS; ++i)
#pragma unroll
        for (int e = 0; e < 8; ++e) af[i][e] = (short)f2bf(acc[i][e] * di);

    // MFMA1: z2 = a2 @ w2
    f32x4 accm[NT1];
#pragma unroll
    for (int nt = 0; nt < NT1; ++nt) accm[nt] = (f32x4){0.f, 0.f, 0.f, 0.f};
    const bf16x8* __restrict__ wf2 = (const bf16x8*)w2f;
#pragma unroll
    for (int ks = 0; ks < KS; ++ks)
#pragma unroll
        for (int nt = 0; nt < NT1; ++nt)
            accm[nt] = __builtin_amdgcn_mfma_f32_16x16x32_bf16(af[ks], wf2[(ks * NT1 + nt) * 64 + lane], accm[nt], 0, 0, 0);

    // h2 = relu(bn2(z2)) -> per-wave LDS tile (C-layout rows -> A-frag reads)
    unsigned short* ot = otile + wid * 16 * OST;
#pragma unroll
    for (int nt = 0; nt < NT1; ++nt) {
        int cc = nt * 16 + m;
        float s = cs[cc], t = ct[cc];
#pragma unroll
        for (int r = 0; r < 4; ++r) {
            float z = fmaxf(accm[nt][r] * s + t, 0.f);
            ot[(q * 4 + r) * OST + cc] = f2bf(z);
        }
    }
    // A2-frags from the wave-private tile (within-wave LDS ordering)
    bf16x8 af2[KS];
#pragma unroll
    for (int ks = 0; ks < KS; ++ks)
        af2[ks] = *(const bf16x8*)&ot[m * OST + ks * 32 + q * 8];

    // MFMA2: t3 = h2 @ w3
    f32x4 acc2[NT2];
#pragma unroll
    for (int nt = 0; nt < NT2; ++nt) acc2[nt] = (f32x4){0.f, 0.f, 0.f, 0.f};
    const bf16x8* __restrict__ wf3 = (const bf16x8*)w3f;
#pragma unroll
    for (int ks = 0; ks < KS; ++ks)
#pragma unroll
        for (int nt = 0; nt < NT2; ++nt)
            acc2[nt] = __builtin_amdgcn_mfma_f32_16x16x32_bf16(af2[ks], wf3[(ks * NT2 + nt) * 64 + lane], acc2[nt], 0, 0, 0);

    float rs[4];
#pragma unroll
    for (int r = 0; r < 4; ++r) rs[r] = dinv[min(rowbase + q * 4 + r, N - 1)];
#pragma unroll
    for (int nt = 0; nt < NT2; ++nt) {
        int cc = nt * 16 + m;
#pragma unroll
        for (int r = 0; r < 4; ++r)
            ot[(q * 4 + r) * OST2 + cc] = f2bf(acc2[nt][r] * rs[r]);
    }
#pragma unroll
    for (int idx = lane; idx < 16 * 8; idx += 64) {
        int rrow = idx >> 3, cc = idx & 7;
        int gr = rowbase + rrow;
        if (gr < N)
            *(uint4*)(out + (size_t)gr * 64 + cc * 8) = *(const uint4*)&ot[rrow * OST2 + cc * 8];
    }
}

// ---------------- layer 3 tail fused: out = log_softmax( relu(bn3(A_hat@t3 + b3)) @ w_out + b_out ) ----------------
__global__ __launch_bounds__(256) void agg_final(
    const unsigned short* __restrict__ hin,
    const int* __restrict__ col, const int* __restrict__ cnt, const float* __restrict__ dinv,
    const float* __restrict__ b3, const float* __restrict__ g3, const float* __restrict__ beta3,
    const float* __restrict__ m3, const float* __restrict__ v3,
    const float* __restrict__ w_out, const float* __restrict__ b_out,
    float* __restrict__ out, int N)
{
    __shared__ float S[64], T[64], sw[64 * 8], sb[8];
    const int tid = threadIdx.x;
    if (tid < 64) {
        float s = g3[tid] * rsqrtf(v3[tid] + BN_EPS);
        S[tid] = s;
        T[tid] = b3[tid] * s + beta3[tid] - m3[tid] * s;
    }
    if (tid < 8) sb[tid] = b_out[tid];
    sw[tid] = w_out[tid];
    sw[tid + 256] = w_out[tid + 256];
    __syncthreads();

    const int wid = tid >> 6, lane = tid & 63;
    const int q = lane >> 4, m = lane & 15;
    const int rowbase = blockIdx.x * 64 + wid * 16;
    const int node = rowbase + m;
    const int nodec = min(node, N - 1);
    const int n = (node < N) ? min(cnt[node], CAP) : 0;
    const int* __restrict__ c = col + (size_t)nodec * CAP;

    float acc[2][8];
#pragma unroll
    for (int i = 0; i < 2; ++i)
#pragma unroll
        for (int e = 0; e < 8; ++e) acc[i][e] = 0.f;

    int p = 0;
    for (; p + 2 <= n; p += 2) {
        const unsigned short* r0 = hin + (size_t)c[p] * 64 + q * 8;
        const unsigned short* r1 = hin + (size_t)c[p + 1] * 64 + q * 8;
        addv(acc[0], *(const uint4*)r0); addv(acc[1], *(const uint4*)(r0 + 32));
        addv(acc[0], *(const uint4*)r1); addv(acc[1], *(const uint4*)(r1 + 32));
    }
    if (p < n) {
        const unsigned short* r0 = hin + (size_t)c[p] * 64 + q * 8;
        addv(acc[0], *(const uint4*)r0);
        addv(acc[1], *(const uint4*)(r0 + 32));
    }

    const float di = dinv[nodec];
    float lg[8];
#pragma unroll
    for (int cc = 0; cc < 8; ++cc) lg[cc] = 0.f;
#pragma unroll
    for (int i = 0; i < 2; ++i) {
        int fbase = i * 32 + q * 8;
#pragma unroll
        for (int j = 0; j < 8; ++j) {
            int f = fbase + j;
            float z = fmaxf((acc[i][j] * di) * S[f] + T[f], 0.f);
#pragma unroll
            for (int cc = 0; cc < 8; ++cc) lg[cc] += z * sw[f * 8 + cc];
        }
    }
    // reduce the 4 q-lanes of each node
#pragma unroll
    for (int cc = 0; cc < 8; ++cc) {
        lg[cc] += __shfl_xor(lg[cc], 16);
        lg[cc] += __shfl_xor(lg[cc], 32);
    }
    if (q == 0 && node < N) {
#pragma unroll
        for (int cc = 0; cc < 8; ++cc) lg[cc] += sb[cc];
        float mx = lg[0];
#pragma unroll
        for (int cc = 1; cc < 8; ++cc) mx = fmaxf(mx, lg[cc]);
        float sum = 0.f;
#pragma unroll
        for (int cc = 0; cc < 8; ++cc) sum += expf(lg[cc] - mx);
        float lse = logf(sum) + mx;
        float4 o0 = {lg[0] - lse, lg[1] - lse, lg[2] - lse, lg[3] - lse};
        float4 o1 = {lg[4] - lse, lg[5] - lse, lg[6] - lse, lg[7] - lse};
        float4* op = (float4*)(out + (size_t)node * 8);
        op[0] = o0;
        op[1] = o1;
    }
}

extern "C" void kernel_launch(void* const* d_in, const int* in_sizes, int n_in,
                              void* d_out, int out_size, void* d_ws, size_t ws_size,
                              hipStream_t stream) {
    const float* x     = (const float*)d_in[0];
    const int*   ei    = (const int*)d_in[1];
    const float* w_in  = (const float*)d_in[2];
    const float* b_in  = (const float*)d_in[3];
    const float* w1    = (const float*)d_in[4];
    const float* b1    = (const float*)d_in[5];
    const float* w2    = (const float*)d_in[6];
    const float* b2    = (const float*)d_in[7];
    const float* w3    = (const float*)d_in[8];
    const float* b3    = (const float*)d_in[9];
    const float* w_o   = (const float*)d_in[10];
    const float* b_o   = (const float*)d_in[11];
    const float* g1    = (const float*)d_in[12];
    const float* be1   = (const float*)d_in[13];
    const float* m1    = (const float*)d_in[14];
    const float* v1    = (const float*)d_in[15];
    const float* g2    = (const float*)d_in[16];
    const float* be2   = (const float*)d_in[17];
    const float* m2    = (const float*)d_in[18];
    const float* v2    = (const float*)d_in[19];
    const float* g3    = (const float*)d_in[20];
    const float* be3   = (const float*)d_in[21];
    const float* m3    = (const float*)d_in[22];
    const float* v3    = (const float*)d_in[23];

    const int N = in_sizes[0] / 128;
    const int E = in_sizes[1] / 2;
    const int K = (N + (1 << BSH) - 1) >> BSH;

    char* p = (char*)d_ws;
    auto alloc = [&](size_t bytes) {
        void* r = (void*)p;
        p += (bytes + 255) & ~(size_t)255;
        return r;
    };
    int*            cnt  = (int*)alloc((size_t)N * 4);
    float*          dinv = (float*)alloc((size_t)N * 4);
    int*            bcnt = (int*)alloc(256 * 4);
    int*            col  = (int*)alloc((size_t)N * CAP * 4);
    uint2*          bins = (uint2*)alloc((size_t)K * BCAP * 8);
    unsigned short* hbA  = (unsigned short*)alloc((size_t)N * 128 * 2);
    unsigned short* hbB  = (unsigned short*)alloc((size_t)N * 128 * 2);
    unsigned short* f_in = (unsigned short*)alloc(8192 * 2);
    unsigned short* f1   = (unsigned short*)alloc(8192 * 2);
    unsigned short* f2   = (unsigned short*)alloc(16384 * 2);
    unsigned short* f3   = (unsigned short*)alloc(8192 * 2);

    const int gB1 = (E + 2047) / 2048;
    const int gM  = (N + 63) / 64;    // 64 nodes/block for all mfma/agg kernels

    // graph build + weight repack
    k_zero<<<1, 256, 0, stream>>>(bcnt, K);
    k_bin<<<gB1, 256, 0, stream>>>(ei, E, K, bins, bcnt);
    k_place<<<K, 1024, 0, stream>>>(bins, bcnt, col, cnt, dinv, N);
    k_repack<<<160, 256, 0, stream>>>(w_in, w1, w2, w3, f_in, f1, f2, f3);

    // h0 = bf16( dinv * relu(x @ w_in + b_in) )                     [N,64]  -> hbA
    mfma_gemm0<<<gM, 256, 0, stream>>>(x, f_in, b_in, dinv, hbA, N);
    // h1 = bf16( dinv * relu(bn1( (A_hat@h0) @ w1 + b1 )) )         [N,128] -> hbB
    agg_mfma1<<<gM, 256, 0, stream>>>(hbA, f1, b1, g1, be1, m1, v1, col, cnt, dinv, hbB, N);
    // t3 = bf16( dinv * ( relu(bn2((A_hat@h1)@w2+b2)) @ w3 ) )      [N,64]  -> hbA
    agg_mfma23<<<gM, 256, 0, stream>>>(hbB, f2, b2, g2, be2, m2, v2, f3, col, cnt, dinv, hbA, N);
    // out = log_softmax( relu(bn3(A_hat@t3 + b3)) @ w_out + b_out ) [N,8]
    agg_final<<<gM, 256, 0, stream>>>(hbA, col, cnt, dinv, b3, g3, be3, m3, v3, w_o, b_o, (float*)d_out, N);
}